// Round 13
// baseline (710.809 us; speedup 1.0000x reference)
//
#include <hip/hip_runtime.h>

#define NN 65536
#define DD 64
#define ND (NN*DD)
#define E0 (NN*8)        // structural out-edges (= transpose-CSR nnz)
#define B1 128           // CSR-build blocks
#define EPB (E0/B1)      // 4096 edges per build block

// sm scratch layout (floats)
enum {
  SM_ACC   = 0,    // [1]=t3 accum (few atomics)
  SM_SCAL  = 4,    // [0]=1/fq [1]=1/fk [2]=1/(fq fk) [3]=b1/fq [4]=1 [5..7]=TR_MAIN [8..10]=TR_ZB2
  SM_KSUM  = 24,   // 66: colsum(k) raw->normalized, [64]=ssq, [65]=ssk
  SM_CHUNK = 96,   // 64
  SM_T2    = 160,  // 2048 per-block t2 partials
  SM_KQ    = 2208,
  SM_G     = SM_KQ + 4096,
  SM_C0    = SM_G + 4096,      // 65x68 stride-68 = 4420
  SM_H     = SM_C0 + 4420,
  SM_Z     = SM_H + 4096,      // 65x64
  SM_ZF    = SM_Z + 4160,
  SM_C     = SM_ZF + 4160,     // 65x65
  SM_CMIX  = SM_C + 4240,
  SM_CFIN  = SM_CMIX + 4240,
  SM_END   = SM_CFIN + 4240
};

#define GP 1008            // gramc0 partial blocks (~4/CU)
#define RP 1024            // redp/Hp partial blocks (4/CU)
#define QKP 1024           // k_qk partial blocks
#define NS 8               // row-chunks for two-level psum
#define GSTRIDE 12616      // ushort stride: 4096 KQ + 4096 G + 4420 C0pad (+pad, 8B-aligned)

__device__ __forceinline__ void f4arr(float4 v, float* a){ a[0]=v.x; a[1]=v.y; a[2]=v.z; a[3]=v.w; }

__device__ __forceinline__ unsigned short f2bf(float f){
  union{float f;unsigned u;}v; v.f=f;
  unsigned r = v.u + 0x7fffu + ((v.u>>16)&1u);
  return (unsigned short)(r>>16);
}
__device__ __forceinline__ float bf2f(unsigned short h){
  union{unsigned u;float f;}v; v.u=((unsigned)h)<<16; return v.f;
}
__device__ __forceinline__ ushort4 pk4(float a, float b, float c, float d){
  ushort4 u; u.x=f2bf(a); u.y=f2bf(b); u.z=f2bf(c); u.w=f2bf(d); return u;
}

// ---------------- Q/K projection (RAW): per-block partials, zero global atomics ----
__global__ __launch_bounds__(256,4) void k_qk(const float* __restrict__ preds,
    const float* __restrict__ Wq, const float* __restrict__ bq,
    const float* __restrict__ Wk, const float* __restrict__ bk,
    float* __restrict__ qout, float* __restrict__ kout, float* __restrict__ slab)
{
  __shared__ float sWq[64*68];
  __shared__ float sWk[64*68];
  __shared__ float sbq[64], sbk[64], sks[64];
  __shared__ float sred[8];
  int t = threadIdx.x;
  for (int i=t;i<4096;i+=256){ int d=i>>6, m=i&63; sWq[m*68+d]=Wq[i]; sWk[m*68+d]=Wk[i]; }
  if (t<64){ sbq[t]=bq[t]; sbk[t]=bk[t]; sks[t]=0.f; }
  __syncthreads();
  int td=t&15, g=t>>4, d0=td*4;
  int base = blockIdx.x*64;
  float aq[16], ak[16];
  #pragma unroll
  for (int i=0;i<4;i++)
    #pragma unroll
    for (int j=0;j<4;j++){ aq[i*4+j]=sbq[d0+j]; ak[i*4+j]=sbk[d0+j]; }
  const float4* pr0=(const float4*)(preds+(size_t)(base+g   )*DD);
  const float4* pr1=(const float4*)(preds+(size_t)(base+g+16)*DD);
  const float4* pr2=(const float4*)(preds+(size_t)(base+g+32)*DD);
  const float4* pr3=(const float4*)(preds+(size_t)(base+g+48)*DD);
  float4 pc0=pr0[0], pc1=pr1[0], pc2=pr2[0], pc3=pr3[0];
  for (int ms=0; ms<16; ms++){
    float4 pn0=pc0,pn1=pc1,pn2=pc2,pn3=pc3;
    if (ms<15){ pn0=pr0[ms+1]; pn1=pr1[ms+1]; pn2=pr2[ms+1]; pn3=pr3[ms+1]; }
    int m=ms*4;
    float wq[4][4], wk[4][4];
    #pragma unroll
    for (int k=0;k<4;k++){ f4arr(*(const float4*)&sWq[(m+k)*68+d0], wq[k]); f4arr(*(const float4*)&sWk[(m+k)*68+d0], wk[k]); }
    float p[4];
    f4arr(pc0,p);
    #pragma unroll
    for (int k=0;k<4;k++)
      #pragma unroll
      for (int j=0;j<4;j++){ aq[0*4+j]+=p[k]*wq[k][j]; ak[0*4+j]+=p[k]*wk[k][j]; }
    f4arr(pc1,p);
    #pragma unroll
    for (int k=0;k<4;k++)
      #pragma unroll
      for (int j=0;j<4;j++){ aq[1*4+j]+=p[k]*wq[k][j]; ak[1*4+j]+=p[k]*wk[k][j]; }
    f4arr(pc2,p);
    #pragma unroll
    for (int k=0;k<4;k++)
      #pragma unroll
      for (int j=0;j<4;j++){ aq[2*4+j]+=p[k]*wq[k][j]; ak[2*4+j]+=p[k]*wk[k][j]; }
    f4arr(pc3,p);
    #pragma unroll
    for (int k=0;k<4;k++)
      #pragma unroll
      for (int j=0;j<4;j++){ aq[3*4+j]+=p[k]*wq[k][j]; ak[3*4+j]+=p[k]*wk[k][j]; }
    pc0=pn0; pc1=pn1; pc2=pn2; pc3=pn3;
  }
  float ssq=0.f, ssk=0.f;
  #pragma unroll
  for (int i=0;i<4;i++){
    int r=base+g+16*i;
    float4 Q=make_float4(aq[i*4+0],aq[i*4+1],aq[i*4+2],aq[i*4+3]);
    float4 K=make_float4(ak[i*4+0],ak[i*4+1],ak[i*4+2],ak[i*4+3]);
    ((float4*)(qout+(size_t)r*DD))[td]=Q;
    ((float4*)(kout+(size_t)r*DD))[td]=K;
    ssq += Q.x*Q.x+Q.y*Q.y+Q.z*Q.z+Q.w*Q.w;
    ssk += K.x*K.x+K.y*K.y+K.z*K.z+K.w*K.w;
  }
  #pragma unroll
  for (int j=0;j<4;j++){
    float cs = ak[0*4+j]+ak[1*4+j]+ak[2*4+j]+ak[3*4+j];
    atomicAdd(&sks[d0+j], cs);     // LDS atomic only
  }
  #pragma unroll
  for (int off=32;off;off>>=1){ ssq+=__shfl_down(ssq,off,64); ssk+=__shfl_down(ssk,off,64); }
  if ((t&63)==0){ sred[t>>6]=ssq; sred[4+(t>>6)]=ssk; }
  __syncthreads();
  float* my = slab + (size_t)blockIdx.x*66;
  if (t<64) my[t]=sks[t];
  if (t==0){ my[64]=sred[0]+sred[1]+sred[2]+sred[3]; my[65]=sred[4]+sred[5]+sred[6]+sred[7]; }
}

// wave-per-column partial-slab sum (fp32 slab) — only for tiny n (qk: n=66)
__global__ __launch_bounds__(256) void k_psumW(const float* __restrict__ slab, int stride, int n, int P,
                                               float* __restrict__ out)
{
  int col=blockIdx.x*4+(threadIdx.x>>6);
  int lane=threadIdx.x&63;
  if (col>=n) return;
  float a0=0.f,a1=0.f;
  int p=lane;
  for (; p+64<P; p+=128){ a0+=slab[(size_t)p*stride+col]; a1+=slab[(size_t)(p+64)*stride+col]; }
  for (; p<P; p+=64) a0+=slab[(size_t)p*stride+col];
  float a=a0+a1;
  #pragma unroll
  for (int off=32;off;off>>=1) a+=__shfl_down(a,off,64);
  if (lane==0) out[col]=a;
}

// Coalesced two-level bf16-slab reduction.
// L1: part[rc][col] = sum_{p in chunk rc} bf2f(slab[p*stride+col]); thread-per-column (coalesced).
__global__ __launch_bounds__(256) void k_psumL1(const unsigned short* __restrict__ slab, int stride, int n, int P,
                                                float* __restrict__ part)
{
  int col=blockIdx.x*256+threadIdx.x;
  if (col>=n) return;
  int rc=blockIdx.y;
  int cp=P/NS;
  int p0=rc*cp;
  const unsigned short* p=slab+(size_t)p0*stride+col;
  float a0=0,a1=0;
  int i=0;
  for (; i+2<=cp; i+=2){ a0+=bf2f(p[0]); a1+=bf2f(p[(size_t)stride]); p+=(size_t)2*stride; }
  for (; i<cp; i++){ a0+=bf2f(p[0]); p+=(size_t)stride; }
  part[(size_t)rc*n+col]=a0+a1;
}
// L2: out[col] = sum_rc part[rc][col]
__global__ __launch_bounds__(256) void k_psumL2(const float* __restrict__ part, int n, float* __restrict__ out)
{
  int col=blockIdx.x*256+threadIdx.x;
  if (col>=n) return;
  float a=0.f;
  #pragma unroll
  for (int rc=0;rc<NS;rc++) a += part[(size_t)rc*n+col];
  out[col]=a;
}

// compute normalization scalars; normalize ksum in place
__global__ void k_scalars(float* __restrict__ ksum, float* __restrict__ sc, const float* __restrict__ lin2){
  __shared__ float s_ki;
  int t=threadIdx.x;
  if (t==0){
    float fq=sqrtf(ksum[64]), fk=sqrtf(ksum[65]);
    float qi=1.f/fq, ki=1.f/fk;
    sc[0]=qi; sc[1]=ki; sc[2]=qi*ki; sc[3]=lin2[1]*qi; sc[4]=1.f;
    sc[5]=ki;    sc[6]=1.f; sc[7]=qi;   // TR_MAIN {in_top,in_bot,out_top}
    sc[8]=qi*ki; sc[9]=qi;  sc[10]=qi;  // TR_ZB2
    s_ki=ki;
  }
  __syncthreads();
  if (t<64) ksum[t]*=s_ki;
}

// Stage1 merged RAW partials of KQ, G, C0 — 16-row tiles; register-based invn; bf16 slab.
__global__ __launch_bounds__(256) void k_gramc0p(const float* __restrict__ qn, const float* __restrict__ kn,
    const float* __restrict__ ksum, const float* __restrict__ sc,
    float* __restrict__ invn, unsigned short* __restrict__ slab)
{
  __shared__ float sk[16][64], sq[16][64], sw[16], sks[64];
  int t=threadIdx.x, tp=t&15, tm=t>>4;
  if (t<64) sks[t]=ksum[t];
  float qi_=sc[0];
  float akq[16], ag[16], ac0[16];
  #pragma unroll
  for (int i=0;i<16;i++){akq[i]=0.f;ag[i]=0.f;ac0[i]=0.f;}
  float rb[4]={0,0,0,0}, cb[4]={0,0,0,0}; float s22=0.f;
  int srow=t>>4, scol=(t&15)*4;   // this thread stages sq row srow, cols scol..scol+3
  for (int tile=blockIdx.x; tile<NN/16; tile+=gridDim.x){
    int base=tile*16;
    ((float4*)sk)[t]=((const float4*)(kn+(size_t)base*DD))[t];
    float4 qv=((const float4*)(qn+(size_t)base*DD))[t];
    ((float4*)sq)[t]=qv;
    {
      // invn for row srow from registers: dot(q_row, ksum_n) via 16-lane xor reduce
      float p = qv.x*sks[scol] + qv.y*sks[scol+1] + qv.z*sks[scol+2] + qv.w*sks[scol+3];
      p += __shfl_xor(p,1,64); p += __shfl_xor(p,2,64);
      p += __shfl_xor(p,4,64); p += __shfl_xor(p,8,64);
      if ((t&15)==0){
        float w = 1.f/(p*qi_ + (float)NN);
        sw[srow]=w; invn[base+srow]=w;
      }
    }
    __syncthreads();
    #pragma unroll
    for (int r=0;r<16;r++){
      float w=sw[r];
      float km[4],qp[4],kp[4];
      f4arr(((const float4*)&sk[r][0])[tm], km);
      f4arr(((const float4*)&sq[r][0])[tp], qp);
      f4arr(((const float4*)&sk[r][0])[tp], kp);
      float wq[4]={w*qp[0],w*qp[1],w*qp[2],w*qp[3]};
      #pragma unroll
      for (int i=0;i<4;i++)
        #pragma unroll
        for (int j=0;j<4;j++){
          akq[i*4+j]+=km[i]*qp[j];
          ag [i*4+j]+=km[i]*kp[j];
          ac0[i*4+j]+=km[i]*wq[j];
        }
      if (tp==0){
        #pragma unroll
        for (int i=0;i<4;i++) rb[i]+=km[i]*w;
      }
      if (tm==0){
        #pragma unroll
        for (int j=0;j<4;j++) cb[j]+=wq[j];
      }
      if (t==0) s22+=w;
    }
    __syncthreads();
  }
  unsigned short* my = slab + (size_t)blockIdx.x*GSTRIDE;
  #pragma unroll
  for (int i=0;i<4;i++){
    int a=tm*4+i;
    *(ushort4*)(my +        a*DD + tp*4) = pk4(akq[i*4+0],akq[i*4+1],akq[i*4+2],akq[i*4+3]);
    *(ushort4*)(my + 4096 + a*DD + tp*4) = pk4(ag [i*4+0],ag [i*4+1],ag [i*4+2],ag [i*4+3]);
    *(ushort4*)(my + 8192 + a*68 + tp*4) = pk4(ac0[i*4+0],ac0[i*4+1],ac0[i*4+2],ac0[i*4+3]);
  }
  if (tp==0){
    #pragma unroll
    for (int i=0;i<4;i++) my[8192 + (tm*4+i)*68 + 64] = f2bf(rb[i]);
  }
  if (tm==0){
    *(ushort4*)(my + 8192 + 64*68 + tp*4) = pk4(cb[0],cb[1],cb[2],cb[3]);
  }
  if (t==0) my[8192 + 64*68 + 64] = f2bf(s22);
}

// normalize KQ, G, C0(stride-68) by the frobenius scalars
__global__ void k_applyscale(float* __restrict__ KQ, float* __restrict__ G, float* __restrict__ C0,
                             const float* __restrict__ sc){
  int i=blockIdx.x*256+threadIdx.x;
  float qi=sc[0], ki=sc[1], qk=sc[2];
  if (i<4096){ KQ[i]*=qk; G[i]*=ki*ki; }
  if (i<4420){
    int a=i/68, b=i-68*a;
    float s = (a<64)? (b<64? qk : ki) : (b<64? qi : 1.f);
    C0[i]*=s;
  }
}

// Stage1 partials of H — 16-row tiles, bf16 slab
__global__ __launch_bounds__(256) void k_Hp(const float* __restrict__ q2, const float* __restrict__ wv,
                                            unsigned short* __restrict__ slab)
{
  __shared__ float sq[16][64], sw[16];
  int t=threadIdx.x, tp=t&15, tm=t>>4;
  float acc[16];
  #pragma unroll
  for (int i=0;i<16;i++) acc[i]=0.f;
  for (int tile=blockIdx.x; tile<NN/16; tile+=gridDim.x){
    int base=tile*16;
    ((float4*)sq)[t]=((const float4*)(q2+(size_t)base*DD))[t];
    if (t<16) sw[t]=wv[base+t];
    __syncthreads();
    #pragma unroll
    for (int r=0;r<16;r++){
      float w=sw[r]; w=w*w;
      float qm[4],qp[4];
      f4arr(((const float4*)&sq[r][0])[tm], qm);
      f4arr(((const float4*)&sq[r][0])[tp], qp);
      float wq[4]={w*qp[0],w*qp[1],w*qp[2],w*qp[3]};
      #pragma unroll
      for (int i=0;i<4;i++)
        #pragma unroll
        for (int j=0;j<4;j++) acc[i*4+j]+=qm[i]*wq[j];
    }
    __syncthreads();
  }
  unsigned short* my = slab + (size_t)blockIdx.x*4096;
  #pragma unroll
  for (int i=0;i<4;i++)
    *(ushort4*)(my + (tm*4+i)*DD + tp*4) = pk4(acc[i*4+0],acc[i*4+1],acc[i*4+2],acc[i*4+3]);
}

// Stage1 RAW partials of z — 16-row tiles, bf16 slab
__global__ __launch_bounds__(256) void k_redp(const float* __restrict__ kn, const float* __restrict__ v,
                                              unsigned short* __restrict__ slab)
{
  __shared__ float sk[16][64], sv[16][64];
  int t=threadIdx.x, tp=t&15, tm=t>>4;
  float acc[16];
  #pragma unroll
  for (int i=0;i<16;i++) acc[i]=0.f;
  float cs[4]={0,0,0,0};
  for (int tile=blockIdx.x; tile<NN/16; tile+=gridDim.x){
    int base=tile*16;
    ((float4*)sk)[t]=((const float4*)(kn+(size_t)base*DD))[t];
    ((float4*)sv)[t]=((const float4*)(v+(size_t)base*DD))[t];
    __syncthreads();
    #pragma unroll
    for (int r=0;r<16;r++){
      float km[4],vd[4];
      f4arr(((const float4*)&sk[r][0])[tm], km);
      f4arr(((const float4*)&sv[r][0])[tp], vd);
      #pragma unroll
      for (int i=0;i<4;i++)
        #pragma unroll
        for (int j=0;j<4;j++) acc[i*4+j]+=km[i]*vd[j];
      if (tm==0){
        #pragma unroll
        for (int j=0;j<4;j++) cs[j]+=vd[j];
      }
    }
    __syncthreads();
  }
  unsigned short* my = slab + (size_t)blockIdx.x*4160;
  #pragma unroll
  for (int i=0;i<4;i++)
    *(ushort4*)(my + (tm*4+i)*DD + tp*4) = pk4(acc[i*4+0],acc[i*4+1],acc[i*4+2],acc[i*4+3]);
  if (tm==0){
    *(ushort4*)(my + 64*DD + tp*4) = pk4(cs[0],cs[1],cs[2],cs[3]);
  }
}

// zf = Cfin * z_scaled with scalar folding. sc3: {in_top, in_bot, out_top}
__global__ void k_zfin(const float* __restrict__ Cfin, const float* __restrict__ z, float* __restrict__ zf,
                       const float* __restrict__ sc3){
  int a=blockIdx.x, d=threadIdx.x;
  float it=sc3[0], ib=sc3[1], ot=sc3[2];
  float acc=0.f;
  for (int b=0;b<64;b++) acc += Cfin[a*65+b]*z[b*DD+d];
  acc = acc*it + Cfin[a*65+64]*ib*z[64*DD+d];
  zf[a*DD+d] = (a<64? ot:1.f)*acc;
}
__global__ void k_zB(const float* __restrict__ KQ, const float* __restrict__ z, float* __restrict__ zf,
                     const float* __restrict__ sc3){
  int a=blockIdx.x, d=threadIdx.x;
  float it=sc3[0], ib=sc3[1], ot=sc3[2];
  float acc;
  if (a<64){ acc=0.f; for (int m=0;m<64;m++) acc += KQ[a*DD+m]*z[m*DD+d]; acc*=it*ot; }
  else acc = ib*z[64*DD+d];
  zf[a*DD+d]=acc;
}

// out(bf16)[n][d] = sdeg[n]*( c*self[n][d] + invn[n]*( sum_m q_raw[n][m]*Zf[m][d] + Zf[64][d] ) )
// Staged sQ/sZ version; m-loop unroll LIMITED (full unroll -> 256 VGPR, round-7 lesson).
__global__ __launch_bounds__(256) void k_expand(const float* __restrict__ qn,
    const float* __restrict__ Zf, const float* __restrict__ invn, const float* __restrict__ sdeg,
    const float* __restrict__ self, const float* __restrict__ coefp, int cidx,
    unsigned short* __restrict__ outv)
{
  __shared__ float sQ[64*68];
  __shared__ float sZ[65*64];
  int t=threadIdx.x;
  int base=blockIdx.x*64;
  for (int i=t;i<1040;i+=256) ((float4*)sZ)[i]=((const float4*)Zf)[i];
  for (int i=t;i<1024;i+=256){
    int r=i>>4, c4=i&15;
    float4 v=((const float4*)(qn+(size_t)(base+r)*DD))[c4];
    float* dst=&sQ[r*68+c4*4]; dst[0]=v.x;dst[1]=v.y;dst[2]=v.z;dst[3]=v.w;
  }
  __syncthreads();
  int td=t&15, g=t>>4, d0=td*4;
  float acc[16];
  {
    float ones[4]; f4arr(*(const float4*)&sZ[64*DD+d0], ones);
    #pragma unroll
    for (int i=0;i<4;i++)
      #pragma unroll
      for (int j=0;j<4;j++) acc[i*4+j]=ones[j];
  }
  #pragma unroll 2
  for (int m=0;m<64;m+=4){
    float zr[4][4];
    #pragma unroll
    for (int k=0;k<4;k++) f4arr(*(const float4*)&sZ[(m+k)*DD+d0], zr[k]);
    #pragma unroll
    for (int i=0;i<4;i++){
      float p[4]; f4arr(*(const float4*)&sQ[(g+16*i)*68+m], p);
      #pragma unroll
      for (int k=0;k<4;k++)
        #pragma unroll
        for (int j=0;j<4;j++) acc[i*4+j]+=p[k]*zr[k][j];
    }
  }
  bool hasself=(cidx>=0);
  float cc = hasself ? coefp[cidx] : 0.f;
  #pragma unroll
  for (int i=0;i<4;i++){
    int r=base+g+16*i;
    float w=invn[r];
    float sd=sdeg[r];
    float4 o=make_float4(acc[i*4+0]*w,acc[i*4+1]*w,acc[i*4+2]*w,acc[i*4+3]*w);
    if (hasself){
      float4 s4=((const float4*)(self+(size_t)r*DD))[td];
      o.x+=cc*s4.x; o.y+=cc*s4.y; o.z+=cc*s4.z; o.w+=cc*s4.w;
    }
    o.x*=sd; o.y*=sd; o.z*=sd; o.w*=sd;
    ushort4 o4; o4.x=f2bf(o.x); o4.y=f2bf(o.y); o4.z=f2bf(o.z); o4.w=f2bf(o.w);
    ((ushort4*)(outv+(size_t)r*DD))[td]=o4;
  }
}

// ---- tiny 65-dim matrix kernels (C0 is stride-68) ----
__global__ void k_makeC(const float* __restrict__ C0, const float* __restrict__ KQ, float* __restrict__ C){
  int a=blockIdx.x, d=threadIdx.x;
  float acc=0.f;
  for (int m=0;m<64;m++) acc += C0[a*68+m]*KQ[m*DD+d];
  C[a*65+d]=acc;
  if (d==0) C[a*65+64]=C0[a*68+64];
}
__global__ void k_makeCmix(const float* __restrict__ C, const float* __restrict__ lin2, float* __restrict__ Cmix){
  int a=blockIdx.x, c=threadIdx.x;
  if (c>=65) return;
  float b1=lin2[1], b2=lin2[2], b3=lin2[3];
  float acc=0.f;
  for (int b=0;b<65;b++) acc += C[a*65+b]*C[b*65+c];
  float r = b2*C[a*65+c] + b3*acc;
  if (a==c) r += b1;
  Cmix[a*65+c]=r;
}
__global__ void k_makeCfin(const float* __restrict__ KQ, const float* __restrict__ Cmix, float* __restrict__ Cfin){
  int a=blockIdx.x, c=threadIdx.x;
  if (c>=65) return;
  float acc;
  if (a<64){ acc=0.f; for (int m=0;m<64;m++) acc += KQ[a*DD+m]*Cmix[m*65+c]; }
  else acc = Cmix[64*65+c];
  Cfin[a*65+c]=acc;
}

// ---- CSR build of transpose adjacency, zero global atomics ----
__global__ __launch_bounds__(256) void k_hist2(const int* __restrict__ acols, unsigned int* __restrict__ slab){
  __shared__ unsigned int lc[16384];
  int t=threadIdx.x;
  for (int i=t;i<16384;i+=256) lc[i]=0u;
  __syncthreads();
  int e0=blockIdx.x*EPB;
  for (int i=t;i<EPB;i+=256){
    int c=acols[e0+i];
    atomicAdd(&lc[c>>2], 1u<<((c&3)*8));
  }
  __syncthreads();
  unsigned int* my=slab+(size_t)blockIdx.x*16384;
  for (int i=t;i<16384;i+=256) my[i]=lc[i];
}

__global__ __launch_bounds__(256) void k_pscan(unsigned int* __restrict__ slab, int* __restrict__ cnt,
                                               float* __restrict__ sdeg, float* __restrict__ accs){
  int w=blockIdx.x*256+threadIdx.x;
  unsigned int r0=0,r1=0,r2=0,r3=0;
  for (int b=0;b<B1;b++){
    unsigned int v=slab[(size_t)b*16384+w];
    slab[(size_t)b*16384+w] = r0|(r1<<8)|(r2<<16)|(r3<<24);
    r0+=v&255u; r1+=(v>>8)&255u; r2+=(v>>16)&255u; r3+=(v>>24)&255u;
  }
  ((int4*)cnt)[w]=make_int4((int)r0,(int)r1,(int)r2,(int)r3);
  float d0=(float)r0+9.f, d1=(float)r1+9.f, d2=(float)r2+9.f, d3=(float)r3+9.f;
  float s0=1.f/sqrtf(d0), s1=1.f/sqrtf(d1), s2=1.f/sqrtf(d2), s3=1.f/sqrtf(d3);
  ((float4*)sdeg)[w]=make_float4(s0,s1,s2,s3);
  float t3 = 1.f/(d0*d0)+1.f/(d1*d1)+1.f/(d2*d2)+1.f/(d3*d3);
  #pragma unroll
  for (int off=32;off;off>>=1) t3+=__shfl_down(t3,off,64);
  if ((threadIdx.x&63)==0) atomicAdd(&accs[1], t3);
}

__global__ __launch_bounds__(1024) void k_scan(const int* __restrict__ cnt, int* __restrict__ row_start){
  __shared__ int wtot[16];
  int t=threadIdx.x, lane=t&63, wid=t>>6;
  int base=t*64;
  int s=0;
  for (int i=0;i<64;i++) s+=cnt[base+i];
  int tot=s;
  for (int off=1;off<64;off<<=1){ int v=__shfl_up(s,off,64); if(lane>=off) s+=v; }
  if (lane==63) wtot[wid]=s;
  __syncthreads();
  if (t<16){
    int v=wtot[t];
    for (int off=1;off<16;off<<=1){ int u=__shfl_up(v,off,64); if(t>=off) v+=u; }
    wtot[t]=v;
  }
  __syncthreads();
  int excl = s - tot + (wid? wtot[wid-1]:0);
  int run=excl;
  for (int i=0;i<64;i++){ row_start[base+i]=run; run+=cnt[base+i]; }
  if (t==1023) row_start[NN]=run;
}

__global__ __launch_bounds__(256) void k_scatter2(const int* __restrict__ acols,
    const unsigned int* __restrict__ slab, const int* __restrict__ row_start,
    const float* __restrict__ sdeg, unsigned short* __restrict__ ccols16, float* __restrict__ accs){
  __shared__ unsigned int lc[16384];
  int t=threadIdx.x;
  for (int i=t;i<16384;i+=256) lc[i]=0u;
  __syncthreads();
  int e0=blockIdx.x*EPB;
  const unsigned int* my=slab+(size_t)blockIdx.x*16384;
  float t3=0.f;
  for (int i=t;i<EPB;i+=256){
    int e=e0+i;
    int c=acols[e];
    unsigned int sh=(unsigned int)(c&3)*8u;
    unsigned int old=atomicAdd(&lc[c>>2], 1u<<sh);
    unsigned int lp=(old>>sh)&255u;
    unsigned int pref=(my[c>>2]>>sh)&255u;
    int slot=row_start[c]+(int)pref+(int)lp;
    ccols16[slot]=(unsigned short)(e>>3);
    float sp=sdeg[e>>3]*sdeg[c];
    t3 += 2.f*sp*sp;
  }
  #pragma unroll
  for (int off=32;off;off>>=1) t3+=__shfl_down(t3,off,64);
  __shared__ float sred[4];
  if ((t&63)==0) sred[t>>6]=t3;
  __syncthreads();
  if (t==0) atomicAdd(&accs[1], sred[0]+sred[1]+sred[2]+sred[3]);
}

// Structural SpMM over bf16 xs: out[r] = sdeg[r]*( sum_out + sum_in + xs[r] )
__global__ __launch_bounds__(256) void k_spmm2(const int* __restrict__ row_start,
    const unsigned short* __restrict__ ccols16, const int* __restrict__ acols,
    const float* __restrict__ sdeg,
    const unsigned short* __restrict__ xs, float* __restrict__ outv, int wout,
    float* __restrict__ accbuf, const float* __restrict__ coefp, int cidx,
    const float* __restrict__ initsrc, int initc, const float* __restrict__ iscale)
{
  int lane=threadIdx.x&63;
  int row=blockIdx.x*4+(threadIdx.x>>6);
  int s=row_start[row], e=row_start[row+1];
  int din=e-s;
  int dc=din>56?56:din;
  int L=8+dc;
  int myc=0;
  if (lane<8) myc=acols[row*8+lane];
  else if (lane<L) myc=(int)ccols16[s+lane-8];
  float a0=0,a1=0,a2=0,a3=0,a4=0,a5=0,a6=0,a7=0;
  int i=0;
  for (; i+8<=L; i+=8){
    int c0=__shfl(myc,i  ,64), c1=__shfl(myc,i+1,64), c2=__shfl(myc,i+2,64), c3=__shfl(myc,i+3,64);
    int c4=__shfl(myc,i+4,64), c5=__shfl(myc,i+5,64), c6=__shfl(myc,i+6,64), c7=__shfl(myc,i+7,64);
    float v0=bf2f(xs[(size_t)c0*DD+lane]), v1=bf2f(xs[(size_t)c1*DD+lane]);
    float v2=bf2f(xs[(size_t)c2*DD+lane]), v3=bf2f(xs[(size_t)c3*DD+lane]);
    float v4=bf2f(xs[(size_t)c4*DD+lane]), v5=bf2f(xs[(size_t)c5*DD+lane]);
    float v6=bf2f(xs[(size_t)c6*DD+lane]), v7=bf2f(xs[(size_t)c7*DD+lane]);
    a0+=v0; a1+=v1; a2+=v2; a3+=v3; a4+=v4; a5+=v5; a6+=v6; a7+=v7;
  }
  for (; i+4<=L; i+=4){
    int c0=__shfl(myc,i,64), c1=__shfl(myc,i+1,64), c2=__shfl(myc,i+2,64), c3=__shfl(myc,i+3,64);
    a0+=bf2f(xs[(size_t)c0*DD+lane]); a1+=bf2f(xs[(size_t)c1*DD+lane]);
    a2+=bf2f(xs[(size_t)c2*DD+lane]); a3+=bf2f(xs[(size_t)c3*DD+lane]);
  }
  for (; i<L; ++i){
    int c=__shfl(myc,i,64);
    a0 += bf2f(xs[(size_t)c*DD+lane]);
  }
  for (int j=56;j<din;j++){ int c=(int)ccols16[s+j]; a0+=bf2f(xs[(size_t)c*DD+lane]); }
  float acc=((a0+a1)+(a2+a3))+((a4+a5)+(a6+a7));
  acc += bf2f(xs[(size_t)row*DD+lane]);
  acc *= sdeg[row];
  size_t off=(size_t)row*DD+lane;
  if (wout) outv[off]=acc;
  if (cidx>=0){
    float cc=coefp[cidx];
    float base;
    if (initc>=0){
      float isc = iscale ? *iscale : coefp[initc];
      base = isc*initsrc[off];
    } else base = accbuf[off];
    accbuf[off]=base+cc*acc;
  }
}

// kns(bf16)[n][d] = sdeg[n]*k_raw[n][d]*(1/fk)
__global__ __launch_bounds__(256) void k_scalerows(const float4* __restrict__ kn, const float* __restrict__ sdeg,
                                                   const float* __restrict__ sc, unsigned short* __restrict__ kns){
  float ki=sc[1];
  int i=blockIdx.x*256+threadIdx.x;
  int stride=gridDim.x*256;
  for (; i<ND/4; i+=stride){
    float sd=sdeg[i>>4]*ki;
    float4 v=kn[i];
    ushort4 o; o.x=f2bf(sd*v.x); o.y=f2bf(sd*v.y); o.z=f2bf(sd*v.z); o.w=f2bf(sd*v.w);
    ((ushort4*)kns)[i]=o;
  }
}

// per-block partials of t2 = sum_r w[r]*dot(q2[r], (A kn)[r]) — bf16 gathers, no global atomics
__global__ __launch_bounds__(256) void k_t2v(const int* __restrict__ row_start,
    const unsigned short* __restrict__ ccols16, const int* __restrict__ acols,
    const float* __restrict__ sdeg, const unsigned short* __restrict__ kns,
    const float* __restrict__ q2, const float* __restrict__ w, float* __restrict__ t2out)
{
  int lane=threadIdx.x&63;
  int wid=blockIdx.x*4+(threadIdx.x>>6);
  int nw=gridDim.x*4;
  float t=0.f;
  for (int row=wid; row<NN; row+=nw){
    int s=row_start[row], e=row_start[row+1];
    int din=e-s;
    int dc=din>56?56:din;
    int L=8+dc;
    int myc=0;
    if (lane<8) myc=acols[row*8+lane];
    else if (lane<L) myc=(int)ccols16[s+lane-8];
    float a0=0,a1=0,a2=0,a3=0,a4=0,a5=0,a6=0,a7=0;
    int i=0;
    for (; i+8<=L; i+=8){
      int c0=__shfl(myc,i  ,64), c1=__shfl(myc,i+1,64), c2=__shfl(myc,i+2,64), c3=__shfl(myc,i+3,64);
      int c4=__shfl(myc,i+4,64), c5=__shfl(myc,i+5,64), c6=__shfl(myc,i+6,64), c7=__shfl(myc,i+7,64);
      a0+=bf2f(kns[(size_t)c0*DD+lane]); a1+=bf2f(kns[(size_t)c1*DD+lane]);
      a2+=bf2f(kns[(size_t)c2*DD+lane]); a3+=bf2f(kns[(size_t)c3*DD+lane]);
      a4+=bf2f(kns[(size_t)c4*DD+lane]); a5+=bf2f(kns[(size_t)c5*DD+lane]);
      a6+=bf2f(kns[(size_t)c6*DD+lane]); a7+=bf2f(kns[(size_t)c7*DD+lane]);
    }
    for (; i+4<=L; i+=4){
      int c0=__shfl(myc,i,64), c1=__shfl(myc,i+1,64), c2=__shfl(myc,i+2,64), c3=__shfl(myc,i+3,64);
      a0+=bf2f(kns[(size_t)c0*DD+lane]); a1+=bf2f(kns[(size_t)c1*DD+lane]);
      a2+=bf2f(kns[(size_t)c2*DD+lane]); a3+=bf2f(kns[(size_t)c3*DD+lane]);
    }
    for (; i<L; ++i){
      int c=__shfl(myc,i,64);
      a0 += bf2f(kns[(size_t)c*DD+lane]);
    }
    for (int j=56;j<din;j++){ int c=(int)ccols16[s+j]; a0+=bf2f(kns[(size_t)c*DD+lane]); }
    float acc=((a0+a1)+(a2+a3))+((a4+a5)+(a6+a7));
    acc += bf2f(kns[(size_t)row*DD+lane]);
    t += w[row]*q2[(size_t)row*DD+lane]*sdeg[row]*acc;
  }
  #pragma unroll
  for (int off=32;off;off>>=1) t+=__shfl_down(t,off,64);
  __shared__ float sred[4];
  if ((threadIdx.x&63)==0) sred[threadIdx.x>>6]=t;
  __syncthreads();
  if (threadIdx.x==0) t2out[blockIdx.x]=sred[0]+sred[1]+sred[2]+sred[3];
}

// per-chunk inverse frobenius of gq (64 chunks of 1024 rows)
__global__ __launch_bounds__(256) void k_chunk(const float* __restrict__ gq, float* __restrict__ chunk_inv){
  int c=blockIdx.x;
  const float4* p=(const float4*)(gq + (size_t)c*65536);
  float ss=0.f;
  for (int i=threadIdx.x;i<16384;i+=256){ float4 v=p[i]; ss += v.x*v.x+v.y*v.y+v.z*v.z+v.w*v.w; }
  __shared__ float red[4];
  #pragma unroll
  for (int off=32;off;off>>=1) ss+=__shfl_down(ss,off,64);
  if ((threadIdx.x&63)==0) red[threadIdx.x>>6]=ss;
  __syncthreads();
  if (threadIdx.x==0){ float s=red[0]+red[1]+red[2]+red[3]; chunk_inv[c]=1.f/sqrtf(s); }
}

// gq *= chunk_inv (-> qn2); nrm2inv[row]=1/(qn2.ksum_n + R)
__global__ __launch_bounds__(256) void k_nrm2(float* __restrict__ gq, const float* __restrict__ chunk_inv,
                                              const float* __restrict__ ks, float* __restrict__ nrm2inv){
  __shared__ float sks[64];
  if (threadIdx.x<64) sks[threadIdx.x]=ks[threadIdx.x];
  __syncthreads();
  int lane=threadIdx.x&63;
  int wid=blockIdx.x*4+(threadIdx.x>>6);
  int nw=gridDim.x*4;
  for (int row=wid;row<NN;row+=nw){
    float q=gq[(size_t)row*DD+lane]*chunk_inv[row>>10];
    gq[(size_t)row*DD+lane]=q;
    float p=q*sks[lane];
    #pragma unroll
    for (int off=32;off;off>>=1) p+=__shfl_down(p,off,64);
    if (lane==0) nrm2inv[row]=1.f/(p+1024.f);
  }
}

__global__ void k_final(const float* __restrict__ G, const float* __restrict__ H,
                        const float* __restrict__ t2s, const float* __restrict__ accs,
                        const float* __restrict__ lin2, float* __restrict__ outv){
  __shared__ float red[256];
  __shared__ float gh;
  int t=threadIdx.x;
  float s=0.f;
  for (int i=t;i<4096;i+=256) s+=G[i]*H[i];
  red[t]=s;
  __syncthreads();
  for (int k=128;k;k>>=1){ if (t<k) red[t]+=red[t+k]; __syncthreads(); }
  if (t==0) gh=red[0];
  __syncthreads();
  float s2=0.f;
  for (int i=t;i<2048;i+=256) s2+=t2s[i];
  red[t]=s2;
  __syncthreads();
  for (int k=128;k;k>>=1){ if (t<k) red[t]+=red[t+k]; __syncthreads(); }
  if (t==0){
    float c0=lin2[0]-1.f;
    outv[0]=sqrtf(gh + 2.f*c0*red[0] + c0*c0*accs[1]);
  }
}

extern "C" void kernel_launch(void* const* d_in, const int* in_sizes, int n_in,
                              void* d_out, int out_size, void* d_ws, size_t ws_size,
                              hipStream_t stream)
{
  (void)n_in; (void)out_size; (void)ws_size; (void)in_sizes;
  const float* preds = (const float*)d_in[0];
  const int*   acols = (const int*)d_in[3];
  const float* Wq    = (const float*)d_in[5];
  const float* bq    = (const float*)d_in[6];
  const float* Wk    = (const float*)d_in[7];
  const float* bk    = (const float*)d_in[8];
  const float* lin1  = (const float*)d_in[9];
  const float* lin2  = (const float*)d_in[10];
  float* outp = (float*)d_out;

  float* W    = (float*)d_ws;
  float* q    = W;                       // RAW query
  float* k    = W + (size_t)ND;          // RAW key
  float* tmpM = W + 2*(size_t)ND;
  unsigned short* mixh = (unsigned short*)(W + 3*(size_t)ND);   // ND ushorts
  float* bufv = W + 3*(size_t)ND + ND/2;
  float* invn = bufv + (size_t)ND;
  float* sdeg = invn + NN;
  float* sm   = sdeg + NN;
  int* cnt       = (int*)(sm + SM_END);
  int* row_start = cnt + NN;
  unsigned short* ccols16 = (unsigned short*)(row_start + NN + 1);
  float* slab = (float*)(ccols16 + E0);             // ~25.7MB region (fp32 view for k_qk)
  unsigned short* slab16 = (unsigned short*)slab;   // bf16 view for gram/red/H partials
  float* part = slab + (size_t)GP*GSTRIDE/2 + 64;   // NS x 12612 fp32 level-1 partials (~0.4MB)

  unsigned int* hist_slab = (unsigned int*)tmpM;  // 8MB, pre-loop only
  unsigned short* knsh = mixh;                    // reuse after last spmm gather

  float* sc=sm+SM_SCAL;
  float* KQ=sm+SM_KQ; float* G=sm+SM_G; float* H=sm+SM_H;
  float* z=sm+SM_Z; float* zf=sm+SM_ZF;
  float* C0=sm+SM_C0; float* C=sm+SM_C; float* Cmix=sm+SM_CMIX; float* Cfin=sm+SM_CFIN;

  hipMemsetAsync(sm, 0, 24*sizeof(float), stream);   // accs + scal

  k_qk<<<QKP,256,0,stream>>>(preds,Wq,bq,Wk,bk,q,k,slab);
  k_psumW<<<(66+3)/4,256,0,stream>>>(slab, 66, 66, QKP, sm+SM_KSUM);
  k_scalars<<<1,64,0,stream>>>(sm+SM_KSUM, sc, lin2);
  k_gramc0p<<<GP,256,0,stream>>>(q,k,sm+SM_KSUM,sc,invn,slab16);
  k_psumL1<<<dim3(50,NS),256,0,stream>>>(slab16, GSTRIDE, 12612, GP, part);
  k_psumL2<<<50,256,0,stream>>>(part, 12612, KQ);          // fills KQ,G,C0(68) raw
  k_applyscale<<<18,256,0,stream>>>(KQ,G,C0,sc);
  k_makeC<<<65,64,0,stream>>>(C0,KQ,C);
  k_makeCmix<<<65,128,0,stream>>>(C,lin2,Cmix);
  k_makeCfin<<<65,128,0,stream>>>(KQ,Cmix,Cfin);

  // CSR build of transpose adjacency (zero global atomics)
  k_hist2<<<B1,256,0,stream>>>(acols, hist_slab);
  k_pscan<<<64,256,0,stream>>>(hist_slab, cnt, sdeg, sm+SM_ACC);
  k_scan<<<1,1024,0,stream>>>(cnt, row_start);
  k_scatter2<<<B1,256,0,stream>>>(acols, hist_slab, row_start, sdeg, ccols16, sm+SM_ACC);

  // ----- main Hop-Stack loop -----
  for (int i=1;i<4;i++){
    const float* v = (i==1) ? preds : tmpM;
    k_redp<<<RP,256,0,stream>>>(k,v,slab16);
    k_psumL1<<<dim3(17,NS),256,0,stream>>>(slab16, 4160, 4160, RP, part);
    k_psumL2<<<17,256,0,stream>>>(part, 4160, z);
    k_zfin<<<65,64,0,stream>>>(Cfin,z,zf, sc+5);          // TR_MAIN
    k_expand<<<1024,256,0,stream>>>(q,zf,invn,sdeg,v,lin2,0,mixh);
    if (i==1)
      k_spmm2<<<16384,256,0,stream>>>(row_start,ccols16,acols,sdeg,mixh,tmpM,1,outp,lin1,1,preds,0,nullptr);
    else
      k_spmm2<<<16384,256,0,stream>>>(row_start,ccols16,acols,sdeg,mixh,tmpM,1,outp,lin1,i,nullptr,-1,nullptr);
  }

  // ----- residual loss branch (seed with qn = q_raw/fq, folded scalars) -----
  k_redp<<<RP,256,0,stream>>>(k,q,slab16);
  k_psumL1<<<dim3(17,NS),256,0,stream>>>(slab16, 4160, 4160, RP, part);
  k_psumL2<<<17,256,0,stream>>>(part, 4160, z);
  k_zB<<<65,64,0,stream>>>(KQ,z,zf, sc+8);                // TR_ZB2
  k_expand<<<1024,256,0,stream>>>(q,zf,invn,sdeg,nullptr,nullptr,-1,mixh);
  k_spmm2<<<16384,256,0,stream>>>(row_start,ccols16,acols,sdeg,mixh,bufv,1,tmpM,lin2,2,q,1,sc+3);  // base=(b1/fq)*q_raw
  k_redp<<<RP,256,0,stream>>>(k,bufv,slab16);
  k_psumL1<<<dim3(17,NS),256,0,stream>>>(slab16, 4160, 4160, RP, part);
  k_psumL2<<<17,256,0,stream>>>(part, 4160, z);
  k_zB<<<65,64,0,stream>>>(KQ,z,zf, sc+5);                // TR_MAIN
  k_expand<<<1024,256,0,stream>>>(q,zf,invn,sdeg,nullptr,nullptr,-1,mixh);
  k_spmm2<<<16384,256,0,stream>>>(row_start,ccols16,acols,sdeg,mixh,nullptr,0,tmpM,lin2,3,nullptr,-1,nullptr);

  k_chunk<<<64,256,0,stream>>>(tmpM, sm+SM_CHUNK);
  k_nrm2<<<2048,256,0,stream>>>(tmpM, sm+SM_CHUNK, sm+SM_KSUM, invn);
  k_scalerows<<<1024,256,0,stream>>>((const float4*)k, sdeg, sc, knsh);
  k_Hp<<<RP,256,0,stream>>>(tmpM, invn, slab16);
  k_psumL1<<<dim3(16,NS),256,0,stream>>>(slab16, 4096, 4096, RP, part);
  k_psumL2<<<16,256,0,stream>>>(part, 4096, H);
  k_t2v<<<2048,256,0,stream>>>(row_start,ccols16,acols,sdeg,knsh,tmpM,invn,sm+SM_T2);
  k_final<<<1,256,0,stream>>>(G,H,sm+SM_T2,sm+SM_ACC,lin2,outp+ND);
}

// Round 14
// 663.250 us; speedup vs baseline: 1.0717x; 1.0717x over previous
//
#include <hip/hip_runtime.h>

#define NN 65536
#define DD 64
#define ND (NN*DD)
#define E0 (NN*8)
#define B1 128
#define EPB (E0/B1)

enum {
  SM_ACC   = 0,
  SM_SCAL  = 4,
  SM_KSUM  = 24,
  SM_CHUNK = 96,
  SM_T2    = 160,
  SM_KQ    = 2208,
  SM_G     = SM_KQ + 4096,
  SM_C0    = SM_G + 4096,      // 65x68 stride-68
  SM_H     = SM_C0 + 4420,
  SM_Z     = SM_H + 4096,
  SM_ZF    = SM_Z + 4160,
  SM_C     = SM_ZF + 4160,
  SM_CMIX  = SM_C + 4240,
  SM_CFIN  = SM_CMIX + 4240,
  SM_END   = SM_CFIN + 4240
};

#define GP 1008            // gramc0 partial blocks (bf16 slab)
#define RP 512             // redp/Hp partial blocks (fp32 slab)
#define QKP 1024
#define NS 8
#define GSTRIDE 12616      // ushort stride for gram slab

__device__ __forceinline__ void f4arr(float4 v, float* a){ a[0]=v.x; a[1]=v.y; a[2]=v.z; a[3]=v.w; }

__device__ __forceinline__ unsigned short f2bf(float f){
  union{float f;unsigned u;}v; v.f=f;
  unsigned r = v.u + 0x7fffu + ((v.u>>16)&1u);
  return (unsigned short)(r>>16);
}
__device__ __forceinline__ float bf2f(unsigned short h){
  union{unsigned u;float f;}v; v.u=((unsigned)h)<<16; return v.f;
}
__device__ __forceinline__ ushort4 pk4(float a, float b, float c, float d){
  ushort4 u; u.x=f2bf(a); u.y=f2bf(b); u.z=f2bf(c); u.w=f2bf(d); return u;
}

// ---------------- Q/K projection (RAW): per-block partials, zero global atomics ----
__global__ __launch_bounds__(256,4) void k_qk(const float* __restrict__ preds,
    const float* __restrict__ Wq, const float* __restrict__ bq,
    const float* __restrict__ Wk, const float* __restrict__ bk,
    float* __restrict__ qout, float* __restrict__ kout, float* __restrict__ slab)
{
  __shared__ float sWq[64*68];
  __shared__ float sWk[64*68];
  __shared__ float sbq[64], sbk[64], sks[64];
  __shared__ float sred[8];
  int t = threadIdx.x;
  for (int i=t;i<4096;i+=256){ int d=i>>6, m=i&63; sWq[m*68+d]=Wq[i]; sWk[m*68+d]=Wk[i]; }
  if (t<64){ sbq[t]=bq[t]; sbk[t]=bk[t]; sks[t]=0.f; }
  __syncthreads();
  int td=t&15, g=t>>4, d0=td*4;
  int base = blockIdx.x*64;
  float aq[16], ak[16];
  #pragma unroll
  for (int i=0;i<4;i++)
    #pragma unroll
    for (int j=0;j<4;j++){ aq[i*4+j]=sbq[d0+j]; ak[i*4+j]=sbk[d0+j]; }
  const float4* pr0=(const float4*)(preds+(size_t)(base+g   )*DD);
  const float4* pr1=(const float4*)(preds+(size_t)(base+g+16)*DD);
  const float4* pr2=(const float4*)(preds+(size_t)(base+g+32)*DD);
  const float4* pr3=(const float4*)(preds+(size_t)(base+g+48)*DD);
  float4 pc0=pr0[0], pc1=pr1[0], pc2=pr2[0], pc3=pr3[0];
  for (int ms=0; ms<16; ms++){
    float4 pn0=pc0,pn1=pc1,pn2=pc2,pn3=pc3;
    if (ms<15){ pn0=pr0[ms+1]; pn1=pr1[ms+1]; pn2=pr2[ms+1]; pn3=pr3[ms+1]; }
    int m=ms*4;
    float wq[4][4], wk[4][4];
    #pragma unroll
    for (int k=0;k<4;k++){ f4arr(*(const float4*)&sWq[(m+k)*68+d0], wq[k]); f4arr(*(const float4*)&sWk[(m+k)*68+d0], wk[k]); }
    float p[4];
    f4arr(pc0,p);
    #pragma unroll
    for (int k=0;k<4;k++)
      #pragma unroll
      for (int j=0;j<4;j++){ aq[0*4+j]+=p[k]*wq[k][j]; ak[0*4+j]+=p[k]*wk[k][j]; }
    f4arr(pc1,p);
    #pragma unroll
    for (int k=0;k<4;k++)
      #pragma unroll
      for (int j=0;j<4;j++){ aq[1*4+j]+=p[k]*wq[k][j]; ak[1*4+j]+=p[k]*wk[k][j]; }
    f4arr(pc2,p);
    #pragma unroll
    for (int k=0;k<4;k++)
      #pragma unroll
      for (int j=0;j<4;j++){ aq[2*4+j]+=p[k]*wq[k][j]; ak[2*4+j]+=p[k]*wk[k][j]; }
    f4arr(pc3,p);
    #pragma unroll
    for (int k=0;k<4;k++)
      #pragma unroll
      for (int j=0;j<4;j++){ aq[3*4+j]+=p[k]*wq[k][j]; ak[3*4+j]+=p[k]*wk[k][j]; }
    pc0=pn0; pc1=pn1; pc2=pn2; pc3=pn3;
  }
  float ssq=0.f, ssk=0.f;
  #pragma unroll
  for (int i=0;i<4;i++){
    int r=base+g+16*i;
    float4 Q=make_float4(aq[i*4+0],aq[i*4+1],aq[i*4+2],aq[i*4+3]);
    float4 K=make_float4(ak[i*4+0],ak[i*4+1],ak[i*4+2],ak[i*4+3]);
    ((float4*)(qout+(size_t)r*DD))[td]=Q;
    ((float4*)(kout+(size_t)r*DD))[td]=K;
    ssq += Q.x*Q.x+Q.y*Q.y+Q.z*Q.z+Q.w*Q.w;
    ssk += K.x*K.x+K.y*K.y+K.z*K.z+K.w*K.w;
  }
  #pragma unroll
  for (int j=0;j<4;j++){
    float cs = ak[0*4+j]+ak[1*4+j]+ak[2*4+j]+ak[3*4+j];
    atomicAdd(&sks[d0+j], cs);     // LDS atomic only
  }
  #pragma unroll
  for (int off=32;off;off>>=1){ ssq+=__shfl_down(ssq,off,64); ssk+=__shfl_down(ssk,off,64); }
  if ((t&63)==0){ sred[t>>6]=ssq; sred[4+(t>>6)]=ssk; }
  __syncthreads();
  float* my = slab + (size_t)blockIdx.x*66;
  if (t<64) my[t]=sks[t];
  if (t==0){ my[64]=sred[0]+sred[1]+sred[2]+sred[3]; my[65]=sred[4]+sred[5]+sred[6]+sred[7]; }
}

// wave-per-column fp32 psum — only for tiny n (qk: n=66)
__global__ __launch_bounds__(256) void k_psumW(const float* __restrict__ slab, int stride, int n, int P,
                                               float* __restrict__ out)
{
  int col=blockIdx.x*4+(threadIdx.x>>6);
  int lane=threadIdx.x&63;
  if (col>=n) return;
  float a0=0.f,a1=0.f;
  int p=lane;
  for (; p+64<P; p+=128){ a0+=slab[(size_t)p*stride+col]; a1+=slab[(size_t)(p+64)*stride+col]; }
  for (; p<P; p+=64) a0+=slab[(size_t)p*stride+col];
  float a=a0+a1;
  #pragma unroll
  for (int off=32;off;off>>=1) a+=__shfl_down(a,off,64);
  if (lane==0) out[col]=a;
}

// Coalesced two-level reductions (thread-per-column).
__global__ __launch_bounds__(256) void k_psumL1(const unsigned short* __restrict__ slab, int stride, int n, int P,
                                                float* __restrict__ part)
{
  int col=blockIdx.x*256+threadIdx.x;
  if (col>=n) return;
  int rc=blockIdx.y;
  int cp=P/NS;
  const unsigned short* p=slab+(size_t)(rc*cp)*stride+col;
  float a0=0,a1=0;
  int i=0;
  for (; i+2<=cp; i+=2){ a0+=bf2f(p[0]); a1+=bf2f(p[(size_t)stride]); p+=(size_t)2*stride; }
  for (; i<cp; i++){ a0+=bf2f(p[0]); p+=(size_t)stride; }
  part[(size_t)rc*n+col]=a0+a1;
}
__global__ __launch_bounds__(256) void k_psumL1f(const float* __restrict__ slab, int stride, int n, int P,
                                                 float* __restrict__ part)
{
  int col=blockIdx.x*256+threadIdx.x;
  if (col>=n) return;
  int rc=blockIdx.y;
  int cp=P/NS;
  const float* p=slab+(size_t)(rc*cp)*stride+col;
  float a0=0,a1=0;
  int i=0;
  for (; i+2<=cp; i+=2){ a0+=p[0]; a1+=p[(size_t)stride]; p+=(size_t)2*stride; }
  for (; i<cp; i++){ a0+=p[0]; p+=(size_t)stride; }
  part[(size_t)rc*n+col]=a0+a1;
}
__global__ __launch_bounds__(256) void k_psumL2(const float* __restrict__ part, int n, float* __restrict__ out)
{
  int col=blockIdx.x*256+threadIdx.x;
  if (col>=n) return;
  float a=0.f;
  #pragma unroll
  for (int rc=0;rc<NS;rc++) a += part[(size_t)rc*n+col];
  out[col]=a;
}

// compute normalization scalars; normalize ksum in place
__global__ void k_scalars(float* __restrict__ ksum, float* __restrict__ sc, const float* __restrict__ lin2){
  __shared__ float s_ki;
  int t=threadIdx.x;
  if (t==0){
    float fq=sqrtf(ksum[64]), fk=sqrtf(ksum[65]);
    float qi=1.f/fq, ki=1.f/fk;
    sc[0]=qi; sc[1]=ki; sc[2]=qi*ki; sc[3]=lin2[1]*qi; sc[4]=1.f;
    sc[5]=ki;    sc[6]=1.f; sc[7]=qi;   // TR_MAIN
    sc[8]=qi*ki; sc[9]=qi;  sc[10]=qi;  // TR_ZB2
    s_ki=ki;
  }
  __syncthreads();
  if (t<64) ksum[t]*=s_ki;
}

// gramc0 partials — bf16 slab, GP=1008, register-based invn (round-13 version, measured 46us)
__global__ __launch_bounds__(256) void k_gramc0p(const float* __restrict__ qn, const float* __restrict__ kn,
    const float* __restrict__ ksum, const float* __restrict__ sc,
    float* __restrict__ invn, unsigned short* __restrict__ slab)
{
  __shared__ float sk[16][64], sq[16][64], sw[16], sks[64];
  int t=threadIdx.x, tp=t&15, tm=t>>4;
  if (t<64) sks[t]=ksum[t];
  float qi_=sc[0];
  float akq[16], ag[16], ac0[16];
  #pragma unroll
  for (int i=0;i<16;i++){akq[i]=0.f;ag[i]=0.f;ac0[i]=0.f;}
  float rb[4]={0,0,0,0}, cb[4]={0,0,0,0}; float s22=0.f;
  int srow=t>>4, scol=(t&15)*4;
  for (int tile=blockIdx.x; tile<NN/16; tile+=gridDim.x){
    int base=tile*16;
    ((float4*)sk)[t]=((const float4*)(kn+(size_t)base*DD))[t];
    float4 qv=((const float4*)(qn+(size_t)base*DD))[t];
    ((float4*)sq)[t]=qv;
    {
      float p = qv.x*sks[scol] + qv.y*sks[scol+1] + qv.z*sks[scol+2] + qv.w*sks[scol+3];
      p += __shfl_xor(p,1,64); p += __shfl_xor(p,2,64);
      p += __shfl_xor(p,4,64); p += __shfl_xor(p,8,64);
      if ((t&15)==0){
        float w = 1.f/(p*qi_ + (float)NN);
        sw[srow]=w; invn[base+srow]=w;
      }
    }
    __syncthreads();
    #pragma unroll
    for (int r=0;r<16;r++){
      float w=sw[r];
      float km[4],qp[4],kp[4];
      f4arr(((const float4*)&sk[r][0])[tm], km);
      f4arr(((const float4*)&sq[r][0])[tp], qp);
      f4arr(((const float4*)&sk[r][0])[tp], kp);
      float wq[4]={w*qp[0],w*qp[1],w*qp[2],w*qp[3]};
      #pragma unroll
      for (int i=0;i<4;i++)
        #pragma unroll
        for (int j=0;j<4;j++){
          akq[i*4+j]+=km[i]*qp[j];
          ag [i*4+j]+=km[i]*kp[j];
          ac0[i*4+j]+=km[i]*wq[j];
        }
      if (tp==0){
        #pragma unroll
        for (int i=0;i<4;i++) rb[i]+=km[i]*w;
      }
      if (tm==0){
        #pragma unroll
        for (int j=0;j<4;j++) cb[j]+=wq[j];
      }
      if (t==0) s22+=w;
    }
    __syncthreads();
  }
  unsigned short* my = slab + (size_t)blockIdx.x*GSTRIDE;
  #pragma unroll
  for (int i=0;i<4;i++){
    int a=tm*4+i;
    *(ushort4*)(my +        a*DD + tp*4) = pk4(akq[i*4+0],akq[i*4+1],akq[i*4+2],akq[i*4+3]);
    *(ushort4*)(my + 4096 + a*DD + tp*4) = pk4(ag [i*4+0],ag [i*4+1],ag [i*4+2],ag [i*4+3]);
    *(ushort4*)(my + 8192 + a*68 + tp*4) = pk4(ac0[i*4+0],ac0[i*4+1],ac0[i*4+2],ac0[i*4+3]);
  }
  if (tp==0){
    #pragma unroll
    for (int i=0;i<4;i++) my[8192 + (tm*4+i)*68 + 64] = f2bf(rb[i]);
  }
  if (tm==0){
    *(ushort4*)(my + 8192 + 64*68 + tp*4) = pk4(cb[0],cb[1],cb[2],cb[3]);
  }
  if (t==0) my[8192 + 64*68 + 64] = f2bf(s22);
}

// normalize KQ, G, C0(stride-68)
__global__ void k_applyscale(float* __restrict__ KQ, float* __restrict__ G, float* __restrict__ C0,
                             const float* __restrict__ sc){
  int i=blockIdx.x*256+threadIdx.x;
  float qi=sc[0], ki=sc[1], qk=sc[2];
  if (i<4096){ KQ[i]*=qk; G[i]*=ki*ki; }
  if (i<4420){
    int a=i/68, b=i-68*a;
    float s = (a<64)? (b<64? qk : ki) : (b<64? qi : 1.f);
    C0[i]*=s;
  }
}

// H partials — fp32 slab, RP=512 (round-9 version)
__global__ __launch_bounds__(256) void k_Hp(const float* __restrict__ q2, const float* __restrict__ wv,
                                            float* __restrict__ slab)
{
  __shared__ float sq[16][64], sw[16];
  int t=threadIdx.x, tp=t&15, tm=t>>4;
  float acc[16];
  #pragma unroll
  for (int i=0;i<16;i++) acc[i]=0.f;
  for (int tile=blockIdx.x; tile<NN/16; tile+=gridDim.x){
    int base=tile*16;
    ((float4*)sq)[t]=((const float4*)(q2+(size_t)base*DD))[t];
    if (t<16) sw[t]=wv[base+t];
    __syncthreads();
    #pragma unroll
    for (int r=0;r<16;r++){
      float w=sw[r]; w=w*w;
      float qm[4],qp[4];
      f4arr(((const float4*)&sq[r][0])[tm], qm);
      f4arr(((const float4*)&sq[r][0])[tp], qp);
      float wq[4]={w*qp[0],w*qp[1],w*qp[2],w*qp[3]};
      #pragma unroll
      for (int i=0;i<4;i++)
        #pragma unroll
        for (int j=0;j<4;j++) acc[i*4+j]+=qm[i]*wq[j];
    }
    __syncthreads();
  }
  float* my = slab + (size_t)blockIdx.x*4096;
  #pragma unroll
  for (int i=0;i<4;i++)
    #pragma unroll
    for (int j=0;j<4;j++) my[(tm*4+i)*DD+tp*4+j] = acc[i*4+j];
}

// z partials — fp32 slab, RP=512 (round-9 version)
__global__ __launch_bounds__(256) void k_redp(const float* __restrict__ kn, const float* __restrict__ v,
                                              float* __restrict__ slab)
{
  __shared__ float sk[16][64], sv[16][64];
  int t=threadIdx.x, tp=t&15, tm=t>>4;
  float acc[16];
  #pragma unroll
  for (int i=0;i<16;i++) acc[i]=0.f;
  float cs[4]={0,0,0,0};
  for (int tile=blockIdx.x; tile<NN/16; tile+=gridDim.x){
    int base=tile*16;
    ((float4*)sk)[t]=((const float4*)(kn+(size_t)base*DD))[t];
    ((float4*)sv)[t]=((const float4*)(v+(size_t)base*DD))[t];
    __syncthreads();
    #pragma unroll
    for (int r=0;r<16;r++){
      float km[4],vd[4];
      f4arr(((const float4*)&sk[r][0])[tm], km);
      f4arr(((const float4*)&sv[r][0])[tp], vd);
      #pragma unroll
      for (int i=0;i<4;i++)
        #pragma unroll
        for (int j=0;j<4;j++) acc[i*4+j]+=km[i]*vd[j];
      if (tm==0){
        #pragma unroll
        for (int j=0;j<4;j++) cs[j]+=vd[j];
      }
    }
    __syncthreads();
  }
  float* my = slab + (size_t)blockIdx.x*4160;
  #pragma unroll
  for (int i=0;i<4;i++)
    #pragma unroll
    for (int j=0;j<4;j++) my[(tm*4+i)*DD+tp*4+j] = acc[i*4+j];
  if (tm==0){
    #pragma unroll
    for (int j=0;j<4;j++) my[64*DD+tp*4+j] = cs[j];
  }
}

// zf = Cfin * z_scaled with scalar folding
__global__ void k_zfin(const float* __restrict__ Cfin, const float* __restrict__ z, float* __restrict__ zf,
                       const float* __restrict__ sc3){
  int a=blockIdx.x, d=threadIdx.x;
  float it=sc3[0], ib=sc3[1], ot=sc3[2];
  float acc=0.f;
  for (int b=0;b<64;b++) acc += Cfin[a*65+b]*z[b*DD+d];
  acc = acc*it + Cfin[a*65+64]*ib*z[64*DD+d];
  zf[a*DD+d] = (a<64? ot:1.f)*acc;
}
__global__ void k_zB(const float* __restrict__ KQ, const float* __restrict__ z, float* __restrict__ zf,
                     const float* __restrict__ sc3){
  int a=blockIdx.x, d=threadIdx.x;
  float it=sc3[0], ib=sc3[1], ot=sc3[2];
  float acc;
  if (a<64){ acc=0.f; for (int m=0;m<64;m++) acc += KQ[a*DD+m]*z[m*DD+d]; acc*=it*ot; }
  else acc = ib*z[64*DD+d];
  zf[a*DD+d]=acc;
}

// expand — staged sQ/sZ, bounded unroll (round-9 version)
__global__ __launch_bounds__(256) void k_expand(const float* __restrict__ qn,
    const float* __restrict__ Zf, const float* __restrict__ invn, const float* __restrict__ sdeg,
    const float* __restrict__ self, const float* __restrict__ coefp, int cidx,
    unsigned short* __restrict__ outv)
{
  __shared__ float sQ[64*68];
  __shared__ float sZ[65*64];
  int t=threadIdx.x;
  int base=blockIdx.x*64;
  for (int i=t;i<1040;i+=256) ((float4*)sZ)[i]=((const float4*)Zf)[i];
  for (int i=t;i<1024;i+=256){
    int r=i>>4, c4=i&15;
    float4 v=((const float4*)(qn+(size_t)(base+r)*DD))[c4];
    float* dst=&sQ[r*68+c4*4]; dst[0]=v.x;dst[1]=v.y;dst[2]=v.z;dst[3]=v.w;
  }
  __syncthreads();
  int td=t&15, g=t>>4, d0=td*4;
  float acc[16];
  {
    float ones[4]; f4arr(*(const float4*)&sZ[64*DD+d0], ones);
    #pragma unroll
    for (int i=0;i<4;i++)
      #pragma unroll
      for (int j=0;j<4;j++) acc[i*4+j]=ones[j];
  }
  #pragma unroll 2
  for (int m=0;m<64;m+=4){
    float zr[4][4];
    #pragma unroll
    for (int k=0;k<4;k++) f4arr(*(const float4*)&sZ[(m+k)*DD+d0], zr[k]);
    #pragma unroll
    for (int i=0;i<4;i++){
      float p[4]; f4arr(*(const float4*)&sQ[(g+16*i)*68+m], p);
      #pragma unroll
      for (int k=0;k<4;k++)
        #pragma unroll
        for (int j=0;j<4;j++) acc[i*4+j]+=p[k]*zr[k][j];
    }
  }
  bool hasself=(cidx>=0);
  float cc = hasself ? coefp[cidx] : 0.f;
  #pragma unroll
  for (int i=0;i<4;i++){
    int r=base+g+16*i;
    float w=invn[r];
    float sd=sdeg[r];
    float4 o=make_float4(acc[i*4+0]*w,acc[i*4+1]*w,acc[i*4+2]*w,acc[i*4+3]*w);
    if (hasself){
      float4 s4=((const float4*)(self+(size_t)r*DD))[td];
      o.x+=cc*s4.x; o.y+=cc*s4.y; o.z+=cc*s4.z; o.w+=cc*s4.w;
    }
    o.x*=sd; o.y*=sd; o.z*=sd; o.w*=sd;
    ushort4 o4; o4.x=f2bf(o.x); o4.y=f2bf(o.y); o4.z=f2bf(o.z); o4.w=f2bf(o.w);
    ((ushort4*)(outv+(size_t)r*DD))[td]=o4;
  }
}

// ---- tiny 65-dim matrix kernels (C0 stride-68) ----
__global__ void k_makeC(const float* __restrict__ C0, const float* __restrict__ KQ, float* __restrict__ C){
  int a=blockIdx.x, d=threadIdx.x;
  float acc=0.f;
  for (int m=0;m<64;m++) acc += C0[a*68+m]*KQ[m*DD+d];
  C[a*65+d]=acc;
  if (d==0) C[a*65+64]=C0[a*68+64];
}
__global__ void k_makeCmix(const float* __restrict__ C, const float* __restrict__ lin2, float* __restrict__ Cmix){
  int a=blockIdx.x, c=threadIdx.x;
  if (c>=65) return;
  float b1=lin2[1], b2=lin2[2], b3=lin2[3];
  float acc=0.f;
  for (int b=0;b<65;b++) acc += C[a*65+b]*C[b*65+c];
  float r = b2*C[a*65+c] + b3*acc;
  if (a==c) r += b1;
  Cmix[a*65+c]=r;
}
__global__ void k_makeCfin(const float* __restrict__ KQ, const float* __restrict__ Cmix, float* __restrict__ Cfin){
  int a=blockIdx.x, c=threadIdx.x;
  if (c>=65) return;
  float acc;
  if (a<64){ acc=0.f; for (int m=0;m<64;m++) acc += KQ[a*DD+m]*Cmix[m*65+c]; }
  else acc = Cmix[64*65+c];
  Cfin[a*65+c]=acc;
}

// ---- CSR build of transpose adjacency, zero global atomics ----
__global__ __launch_bounds__(256) void k_hist2(const int* __restrict__ acols, unsigned int* __restrict__ slab){
  __shared__ unsigned int lc[16384];
  int t=threadIdx.x;
  for (int i=t;i<16384;i+=256) lc[i]=0u;
  __syncthreads();
  int e0=blockIdx.x*EPB;
  for (int i=t;i<EPB;i+=256){
    int c=acols[e0+i];
    atomicAdd(&lc[c>>2], 1u<<((c&3)*8));
  }
  __syncthreads();
  unsigned int* my=slab+(size_t)blockIdx.x*16384;
  for (int i=t;i<16384;i+=256) my[i]=lc[i];
}

__global__ __launch_bounds__(256) void k_pscan(unsigned int* __restrict__ slab, int* __restrict__ cnt,
                                               float* __restrict__ sdeg, float* __restrict__ accs){
  int w=blockIdx.x*256+threadIdx.x;
  unsigned int r0=0,r1=0,r2=0,r3=0;
  for (int b=0;b<B1;b++){
    unsigned int v=slab[(size_t)b*16384+w];
    slab[(size_t)b*16384+w] = r0|(r1<<8)|(r2<<16)|(r3<<24);
    r0+=v&255u; r1+=(v>>8)&255u; r2+=(v>>16)&255u; r3+=(v>>24)&255u;
  }
  ((int4*)cnt)[w]=make_int4((int)r0,(int)r1,(int)r2,(int)r3);
  float d0=(float)r0+9.f, d1=(float)r1+9.f, d2=(float)r2+9.f, d3=(float)r3+9.f;
  float s0=1.f/sqrtf(d0), s1=1.f/sqrtf(d1), s2=1.f/sqrtf(d2), s3=1.f/sqrtf(d3);
  ((float4*)sdeg)[w]=make_float4(s0,s1,s2,s3);
  float t3 = 1.f/(d0*d0)+1.f/(d1*d1)+1.f/(d2*d2)+1.f/(d3*d3);
  #pragma unroll
  for (int off=32;off;off>>=1) t3+=__shfl_down(t3,off,64);
  if ((threadIdx.x&63)==0) atomicAdd(&accs[1], t3);
}

__global__ __launch_bounds__(1024) void k_scan(const int* __restrict__ cnt, int* __restrict__ row_start){
  __shared__ int wtot[16];
  int t=threadIdx.x, lane=t&63, wid=t>>6;
  int base=t*64;
  int s=0;
  for (int i=0;i<64;i++) s+=cnt[base+i];
  int tot=s;
  for (int off=1;off<64;off<<=1){ int v=__shfl_up(s,off,64); if(lane>=off) s+=v; }
  if (lane==63) wtot[wid]=s;
  __syncthreads();
  if (t<16){
    int v=wtot[t];
    for (int off=1;off<16;off<<=1){ int u=__shfl_up(v,off,64); if(t>=off) v+=u; }
    wtot[t]=v;
  }
  __syncthreads();
  int excl = s - tot + (wid? wtot[wid-1]:0);
  int run=excl;
  for (int i=0;i<64;i++){ row_start[base+i]=run; run+=cnt[base+i]; }
  if (t==1023) row_start[NN]=run;
}

__global__ __launch_bounds__(256) void k_scatter2(const int* __restrict__ acols,
    const unsigned int* __restrict__ slab, const int* __restrict__ row_start,
    const float* __restrict__ sdeg, unsigned short* __restrict__ ccols16, float* __restrict__ accs){
  __shared__ unsigned int lc[16384];
  int t=threadIdx.x;
  for (int i=t;i<16384;i+=256) lc[i]=0u;
  __syncthreads();
  int e0=blockIdx.x*EPB;
  const unsigned int* my=slab+(size_t)blockIdx.x*16384;
  float t3=0.f;
  for (int i=t;i<EPB;i+=256){
    int e=e0+i;
    int c=acols[e];
    unsigned int sh=(unsigned int)(c&3)*8u;
    unsigned int old=atomicAdd(&lc[c>>2], 1u<<sh);
    unsigned int lp=(old>>sh)&255u;
    unsigned int pref=(my[c>>2]>>sh)&255u;
    int slot=row_start[c]+(int)pref+(int)lp;
    ccols16[slot]=(unsigned short)(e>>3);
    float sp=sdeg[e>>3]*sdeg[c];
    t3 += 2.f*sp*sp;
  }
  #pragma unroll
  for (int off=32;off;off>>=1) t3+=__shfl_down(t3,off,64);
  __shared__ float sred[4];
  if ((t&63)==0) sred[t>>6]=t3;
  __syncthreads();
  if (t==0) atomicAdd(&accs[1], sred[0]+sred[1]+sred[2]+sred[3]);
}

// Structural SpMM over bf16 xs
__global__ __launch_bounds__(256) void k_spmm2(const int* __restrict__ row_start,
    const unsigned short* __restrict__ ccols16, const int* __restrict__ acols,
    const float* __restrict__ sdeg,
    const unsigned short* __restrict__ xs, float* __restrict__ outv, int wout,
    float* __restrict__ accbuf, const float* __restrict__ coefp, int cidx,
    const float* __restrict__ initsrc, int initc, const float* __restrict__ iscale)
{
  int lane=threadIdx.x&63;
  int row=blockIdx.x*4+(threadIdx.x>>6);
  int s=row_start[row], e=row_start[row+1];
  int din=e-s;
  int dc=din>56?56:din;
  int L=8+dc;
  int myc=0;
  if (lane<8) myc=acols[row*8+lane];
  else if (lane<L) myc=(int)ccols16[s+lane-8];
  float a0=0,a1=0,a2=0,a3=0,a4=0,a5=0,a6=0,a7=0;
  int i=0;
  for (; i+8<=L; i+=8){
    int c0=__shfl(myc,i  ,64), c1=__shfl(myc,i+1,64), c2=__shfl(myc,i+2,64), c3=__shfl(myc,i+3,64);
    int c4=__shfl(myc,i+4,64), c5=__shfl(myc,i+5,64), c6=__shfl(myc,i+6,64), c7=__shfl(myc,i+7,64);
    float v0=bf2f(xs[(size_t)c0*DD+lane]), v1=bf2f(xs[(size_t)c1*DD+lane]);
    float v2=bf2f(xs[(size_t)c2*DD+lane]), v3=bf2f(xs[(size_t)c3*DD+lane]);
    float v4=bf2f(xs[(size_t)c4*DD+lane]), v5=bf2f(xs[(size_t)c5*DD+lane]);
    float v6=bf2f(xs[(size_t)c6*DD+lane]), v7=bf2f(xs[(size_t)c7*DD+lane]);
    a0+=v0; a1+=v1; a2+=v2; a3+=v3; a4+=v4; a5+=v5; a6+=v6; a7+=v7;
  }
  for (; i+4<=L; i+=4){
    int c0=__shfl(myc,i,64), c1=__shfl(myc,i+1,64), c2=__shfl(myc,i+2,64), c3=__shfl(myc,i+3,64);
    a0+=bf2f(xs[(size_t)c0*DD+lane]); a1+=bf2f(xs[(size_t)c1*DD+lane]);
    a2+=bf2f(xs[(size_t)c2*DD+lane]); a3+=bf2f(xs[(size_t)c3*DD+lane]);
  }
  for (; i<L; ++i){
    int c=__shfl(myc,i,64);
    a0 += bf2f(xs[(size_t)c*DD+lane]);
  }
  for (int j=56;j<din;j++){ int c=(int)ccols16[s+j]; a0+=bf2f(xs[(size_t)c*DD+lane]); }
  float acc=((a0+a1)+(a2+a3))+((a4+a5)+(a6+a7));
  acc += bf2f(xs[(size_t)row*DD+lane]);
  acc *= sdeg[row];
  size_t off=(size_t)row*DD+lane;
  if (wout) outv[off]=acc;
  if (cidx>=0){
    float cc=coefp[cidx];
    float base;
    if (initc>=0){
      float isc = iscale ? *iscale : coefp[initc];
      base = isc*initsrc[off];
    } else base = accbuf[off];
    accbuf[off]=base+cc*acc;
  }
}

// kns(bf16)[n][d] = sdeg[n]*k_raw[n][d]*(1/fk)
__global__ __launch_bounds__(256) void k_scalerows(const float4* __restrict__ kn, const float* __restrict__ sdeg,
                                                   const float* __restrict__ sc, unsigned short* __restrict__ kns){
  float ki=sc[1];
  int i=blockIdx.x*256+threadIdx.x;
  int stride=gridDim.x*256;
  for (; i<ND/4; i+=stride){
    float sd=sdeg[i>>4]*ki;
    float4 v=kn[i];
    ushort4 o; o.x=f2bf(sd*v.x); o.y=f2bf(sd*v.y); o.z=f2bf(sd*v.z); o.w=f2bf(sd*v.w);
    ((ushort4*)kns)[i]=o;
  }
}

// t2 partials — bf16 gathers, no global atomics
__global__ __launch_bounds__(256) void k_t2v(const int* __restrict__ row_start,
    const unsigned short* __restrict__ ccols16, const int* __restrict__ acols,
    const float* __restrict__ sdeg, const unsigned short* __restrict__ kns,
    const float* __restrict__ q2, const float* __restrict__ w, float* __restrict__ t2out)
{
  int lane=threadIdx.x&63;
  int wid=blockIdx.x*4+(threadIdx.x>>6);
  int nw=gridDim.x*4;
  float t=0.f;
  for (int row=wid; row<NN; row+=nw){
    int s=row_start[row], e=row_start[row+1];
    int din=e-s;
    int dc=din>56?56:din;
    int L=8+dc;
    int myc=0;
    if (lane<8) myc=acols[row*8+lane];
    else if (lane<L) myc=(int)ccols16[s+lane-8];
    float a0=0,a1=0,a2=0,a3=0,a4=0,a5=0,a6=0,a7=0;
    int i=0;
    for (; i+8<=L; i+=8){
      int c0=__shfl(myc,i  ,64), c1=__shfl(myc,i+1,64), c2=__shfl(myc,i+2,64), c3=__shfl(myc,i+3,64);
      int c4=__shfl(myc,i+4,64), c5=__shfl(myc,i+5,64), c6=__shfl(myc,i+6,64), c7=__shfl(myc,i+7,64);
      a0+=bf2f(kns[(size_t)c0*DD+lane]); a1+=bf2f(kns[(size_t)c1*DD+lane]);
      a2+=bf2f(kns[(size_t)c2*DD+lane]); a3+=bf2f(kns[(size_t)c3*DD+lane]);
      a4+=bf2f(kns[(size_t)c4*DD+lane]); a5+=bf2f(kns[(size_t)c5*DD+lane]);
      a6+=bf2f(kns[(size_t)c6*DD+lane]); a7+=bf2f(kns[(size_t)c7*DD+lane]);
    }
    for (; i+4<=L; i+=4){
      int c0=__shfl(myc,i,64), c1=__shfl(myc,i+1,64), c2=__shfl(myc,i+2,64), c3=__shfl(myc,i+3,64);
      a0+=bf2f(kns[(size_t)c0*DD+lane]); a1+=bf2f(kns[(size_t)c1*DD+lane]);
      a2+=bf2f(kns[(size_t)c2*DD+lane]); a3+=bf2f(kns[(size_t)c3*DD+lane]);
    }
    for (; i<L; ++i){
      int c=__shfl(myc,i,64);
      a0 += bf2f(kns[(size_t)c*DD+lane]);
    }
    for (int j=56;j<din;j++){ int c=(int)ccols16[s+j]; a0+=bf2f(kns[(size_t)c*DD+lane]); }
    float acc=((a0+a1)+(a2+a3))+((a4+a5)+(a6+a7));
    acc += bf2f(kns[(size_t)row*DD+lane]);
    t += w[row]*q2[(size_t)row*DD+lane]*sdeg[row]*acc;
  }
  #pragma unroll
  for (int off=32;off;off>>=1) t+=__shfl_down(t,off,64);
  __shared__ float sred[4];
  if ((threadIdx.x&63)==0) sred[threadIdx.x>>6]=t;
  __syncthreads();
  if (threadIdx.x==0) t2out[blockIdx.x]=sred[0]+sred[1]+sred[2]+sred[3];
}

// per-chunk inverse frobenius of gq
__global__ __launch_bounds__(256) void k_chunk(const float* __restrict__ gq, float* __restrict__ chunk_inv){
  int c=blockIdx.x;
  const float4* p=(const float4*)(gq + (size_t)c*65536);
  float ss=0.f;
  for (int i=threadIdx.x;i<16384;i+=256){ float4 v=p[i]; ss += v.x*v.x+v.y*v.y+v.z*v.z+v.w*v.w; }
  __shared__ float red[4];
  #pragma unroll
  for (int off=32;off;off>>=1) ss+=__shfl_down(ss,off,64);
  if ((threadIdx.x&63)==0) red[threadIdx.x>>6]=ss;
  __syncthreads();
  if (threadIdx.x==0){ float s=red[0]+red[1]+red[2]+red[3]; chunk_inv[c]=1.f/sqrtf(s); }
}

// gq *= chunk_inv; nrm2inv
__global__ __launch_bounds__(256) void k_nrm2(float* __restrict__ gq, const float* __restrict__ chunk_inv,
                                              const float* __restrict__ ks, float* __restrict__ nrm2inv){
  __shared__ float sks[64];
  if (threadIdx.x<64) sks[threadIdx.x]=ks[threadIdx.x];
  __syncthreads();
  int lane=threadIdx.x&63;
  int wid=blockIdx.x*4+(threadIdx.x>>6);
  int nw=gridDim.x*4;
  for (int row=wid;row<NN;row+=nw){
    float q=gq[(size_t)row*DD+lane]*chunk_inv[row>>10];
    gq[(size_t)row*DD+lane]=q;
    float p=q*sks[lane];
    #pragma unroll
    for (int off=32;off;off>>=1) p+=__shfl_down(p,off,64);
    if (lane==0) nrm2inv[row]=1.f/(p+1024.f);
  }
}

__global__ void k_final(const float* __restrict__ G, const float* __restrict__ H,
                        const float* __restrict__ t2s, const float* __restrict__ accs,
                        const float* __restrict__ lin2, float* __restrict__ outv){
  __shared__ float red[256];
  __shared__ float gh;
  int t=threadIdx.x;
  float s=0.f;
  for (int i=t;i<4096;i+=256) s+=G[i]*H[i];
  red[t]=s;
  __syncthreads();
  for (int k=128;k;k>>=1){ if (t<k) red[t]+=red[t+k]; __syncthreads(); }
  if (t==0) gh=red[0];
  __syncthreads();
  float s2=0.f;
  for (int i=t;i<2048;i+=256) s2+=t2s[i];
  red[t]=s2;
  __syncthreads();
  for (int k=128;k;k>>=1){ if (t<k) red[t]+=red[t+k]; __syncthreads(); }
  if (t==0){
    float c0=lin2[0]-1.f;
    outv[0]=sqrtf(gh + 2.f*c0*red[0] + c0*c0*accs[1]);
  }
}

extern "C" void kernel_launch(void* const* d_in, const int* in_sizes, int n_in,
                              void* d_out, int out_size, void* d_ws, size_t ws_size,
                              hipStream_t stream)
{
  (void)n_in; (void)out_size; (void)ws_size; (void)in_sizes;
  const float* preds = (const float*)d_in[0];
  const int*   acols = (const int*)d_in[3];
  const float* Wq    = (const float*)d_in[5];
  const float* bq    = (const float*)d_in[6];
  const float* Wk    = (const float*)d_in[7];
  const float* bk    = (const float*)d_in[8];
  const float* lin1  = (const float*)d_in[9];
  const float* lin2  = (const float*)d_in[10];
  float* outp = (float*)d_out;

  float* W    = (float*)d_ws;
  float* q    = W;
  float* k    = W + (size_t)ND;
  float* tmpM = W + 2*(size_t)ND;
  unsigned short* mixh = (unsigned short*)(W + 3*(size_t)ND);
  float* bufv = W + 3*(size_t)ND + ND/2;
  float* invn = bufv + (size_t)ND;
  float* sdeg = invn + NN;
  float* sm   = sdeg + NN;
  int* cnt       = (int*)(sm + SM_END);
  int* row_start = cnt + NN;
  unsigned short* ccols16 = (unsigned short*)(row_start + NN + 1);
  float* slab = (float*)(ccols16 + E0);             // ~26MB region: fp32 view (qk, redp, Hp)
  unsigned short* slab16 = (unsigned short*)slab;   // bf16 view (gramc0p)
  float* part = slab + (size_t)GP*GSTRIDE/2 + 64;   // NS x 12612 fp32 L1 partials

  unsigned int* hist_slab = (unsigned int*)tmpM;
  unsigned short* knsh = mixh;

  float* sc=sm+SM_SCAL;
  float* KQ=sm+SM_KQ; float* G=sm+SM_G; float* H=sm+SM_H;
  float* z=sm+SM_Z; float* zf=sm+SM_ZF;
  float* C0=sm+SM_C0; float* C=sm+SM_C; float* Cmix=sm+SM_CMIX; float* Cfin=sm+SM_CFIN;

  hipMemsetAsync(sm, 0, 24*sizeof(float), stream);

  k_qk<<<QKP,256,0,stream>>>(preds,Wq,bq,Wk,bk,q,k,slab);
  k_psumW<<<(66+3)/4,256,0,stream>>>(slab, 66, 66, QKP, sm+SM_KSUM);
  k_scalars<<<1,64,0,stream>>>(sm+SM_KSUM, sc, lin2);
  k_gramc0p<<<GP,256,0,stream>>>(q,k,sm+SM_KSUM,sc,invn,slab16);
  k_psumL1<<<dim3(50,NS),256,0,stream>>>(slab16, GSTRIDE, 12612, GP, part);
  k_psumL2<<<50,256,0,stream>>>(part, 12612, KQ);   // fills KQ,G,C0(68) raw
  k_applyscale<<<18,256,0,stream>>>(KQ,G,C0,sc);
  k_makeC<<<65,64,0,stream>>>(C0,KQ,C);
  k_makeCmix<<<65,128,0,stream>>>(C,lin2,Cmix);
  k_makeCfin<<<65,128,0,stream>>>(KQ,Cmix,Cfin);

  // CSR build of transpose adjacency (zero global atomics)
  k_hist2<<<B1,256,0,stream>>>(acols, hist_slab);
  k_pscan<<<64,256,0,stream>>>(hist_slab, cnt, sdeg, sm+SM_ACC);
  k_scan<<<1,1024,0,stream>>>(cnt, row_start);
  k_scatter2<<<B1,256,0,stream>>>(acols, hist_slab, row_start, sdeg, ccols16, sm+SM_ACC);

  // ----- main Hop-Stack loop -----
  for (int i=1;i<4;i++){
    const float* v = (i==1) ? preds : tmpM;
    k_redp<<<RP,256,0,stream>>>(k,v,slab);
    k_psumL1f<<<dim3(17,NS),256,0,stream>>>(slab, 4160, 4160, RP, part);
    k_psumL2<<<17,256,0,stream>>>(part, 4160, z);
    k_zfin<<<65,64,0,stream>>>(Cfin,z,zf, sc+5);
    k_expand<<<1024,256,0,stream>>>(q,zf,invn,sdeg,v,lin2,0,mixh);
    if (i==1)
      k_spmm2<<<16384,256,0,stream>>>(row_start,ccols16,acols,sdeg,mixh,tmpM,1,outp,lin1,1,preds,0,nullptr);
    else
      k_spmm2<<<16384,256,0,stream>>>(row_start,ccols16,acols,sdeg,mixh,tmpM,1,outp,lin1,i,nullptr,-1,nullptr);
  }

  // ----- residual loss branch -----
  k_redp<<<RP,256,0,stream>>>(k,q,slab);
  k_psumL1f<<<dim3(17,NS),256,0,stream>>>(slab, 4160, 4160, RP, part);
  k_psumL2<<<17,256,0,stream>>>(part, 4160, z);
  k_zB<<<65,64,0,stream>>>(KQ,z,zf, sc+8);
  k_expand<<<1024,256,0,stream>>>(q,zf,invn,sdeg,nullptr,nullptr,-1,mixh);
  k_spmm2<<<16384,256,0,stream>>>(row_start,ccols16,acols,sdeg,mixh,bufv,1,tmpM,lin2,2,q,1,sc+3);
  k_redp<<<RP,256,0,stream>>>(k,bufv,slab);
  k_psumL1f<<<dim3(17,NS),256,0,stream>>>(slab, 4160, 4160, RP, part);
  k_psumL2<<<17,256,0,stream>>>(part, 4160, z);
  k_zB<<<65,64,0,stream>>>(KQ,z,zf, sc+5);
  k_expand<<<1024,256,0,stream>>>(q,zf,invn,sdeg,nullptr,nullptr,-1,mixh);
  k_spmm2<<<16384,256,0,stream>>>(row_start,ccols16,acols,sdeg,mixh,nullptr,0,tmpM,lin2,3,nullptr,-1,nullptr);

  k_chunk<<<64,256,0,stream>>>(tmpM, sm+SM_CHUNK);
  k_nrm2<<<2048,256,0,stream>>>(tmpM, sm+SM_CHUNK, sm+SM_KSUM, invn);
  k_scalerows<<<1024,256,0,stream>>>((const float4*)k, sdeg, sc, knsh);
  k_Hp<<<RP,256,0,stream>>>(tmpM, invn, slab);
  k_psumL1f<<<dim3(16,NS),256,0,stream>>>(slab, 4096, 4096, RP, part);
  k_psumL2<<<16,256,0,stream>>>(part, 4096, H);
  k_t2v<<<2048,256,0,stream>>>(row_start,ccols16,acols,sdeg,knsh,tmpM,invn,sm+SM_T2);
  k_final<<<1,256,0,stream>>>(G,H,sm+SM_T2,sm+SM_ACC,lin2,outp+ND);
}

// Round 15
// 661.069 us; speedup vs baseline: 1.0752x; 1.0033x over previous
//
#include <hip/hip_runtime.h>

#define NN 65536
#define DD 64
#define ND (NN*DD)
#define E0 (NN*8)
#define B1 128
#define EPB (E0/B1)

enum {
  SM_ACC   = 0,
  SM_SCAL  = 4,
  SM_KSUM  = 24,
  SM_CHUNK = 96,
  SM_T2    = 160,
  SM_KQ    = 2208,
  SM_G     = SM_KQ + 4096,
  SM_C0    = SM_G + 4096,      // 65x68 stride-68
  SM_H     = SM_C0 + 4420,
  SM_Z     = SM_H + 4096,
  SM_ZF    = SM_Z + 4160,
  SM_C     = SM_ZF + 4160,
  SM_CMIX  = SM_C + 4240,
  SM_CFIN  = SM_CMIX + 4240,
  SM_END   = SM_CFIN + 4240
};

#define GP 1008            // gramc0 partial blocks (bf16 slab)
#define RP 512             // redp/Hp partial blocks (fp32 slab)
#define QKP 1024
#define NS 8
#define GSTRIDE 12616      // ushort stride for gram slab

__device__ __forceinline__ void f4arr(float4 v, float* a){ a[0]=v.x; a[1]=v.y; a[2]=v.z; a[3]=v.w; }

__device__ __forceinline__ unsigned short f2bf(float f){
  union{float f;unsigned u;}v; v.f=f;
  unsigned r = v.u + 0x7fffu + ((v.u>>16)&1u);
  return (unsigned short)(r>>16);
}
__device__ __forceinline__ float bf2f(unsigned short h){
  union{unsigned u;float f;}v; v.u=((unsigned)h)<<16; return v.f;
}
__device__ __forceinline__ ushort4 pk4(float a, float b, float c, float d){
  ushort4 u; u.x=f2bf(a); u.y=f2bf(b); u.z=f2bf(c); u.w=f2bf(d); return u;
}
__device__ __forceinline__ float4 up4(ushort4 u){
  return make_float4(bf2f(u.x),bf2f(u.y),bf2f(u.z),bf2f(u.w));
}

// ---------------- Q/K projection (RAW): q fp32 (loss seed) + qh/kh bf16; per-block partials ----
__global__ __launch_bounds__(256,4) void k_qk(const float* __restrict__ preds,
    const float* __restrict__ Wq, const float* __restrict__ bq,
    const float* __restrict__ Wk, const float* __restrict__ bk,
    float* __restrict__ qout, unsigned short* __restrict__ qh, unsigned short* __restrict__ kh,
    float* __restrict__ slab)
{
  __shared__ float sWq[64*68];
  __shared__ float sWk[64*68];
  __shared__ float sbq[64], sbk[64], sks[64];
  __shared__ float sred[8];
  int t = threadIdx.x;
  for (int i=t;i<4096;i+=256){ int d=i>>6, m=i&63; sWq[m*68+d]=Wq[i]; sWk[m*68+d]=Wk[i]; }
  if (t<64){ sbq[t]=bq[t]; sbk[t]=bk[t]; sks[t]=0.f; }
  __syncthreads();
  int td=t&15, g=t>>4, d0=td*4;
  int base = blockIdx.x*64;
  float aq[16], ak[16];
  #pragma unroll
  for (int i=0;i<4;i++)
    #pragma unroll
    for (int j=0;j<4;j++){ aq[i*4+j]=sbq[d0+j]; ak[i*4+j]=sbk[d0+j]; }
  const float4* pr0=(const float4*)(preds+(size_t)(base+g   )*DD);
  const float4* pr1=(const float4*)(preds+(size_t)(base+g+16)*DD);
  const float4* pr2=(const float4*)(preds+(size_t)(base+g+32)*DD);
  const float4* pr3=(const float4*)(preds+(size_t)(base+g+48)*DD);
  float4 pc0=pr0[0], pc1=pr1[0], pc2=pr2[0], pc3=pr3[0];
  for (int ms=0; ms<16; ms++){
    float4 pn0=pc0,pn1=pc1,pn2=pc2,pn3=pc3;
    if (ms<15){ pn0=pr0[ms+1]; pn1=pr1[ms+1]; pn2=pr2[ms+1]; pn3=pr3[ms+1]; }
    int m=ms*4;
    float wq[4][4], wk[4][4];
    #pragma unroll
    for (int k=0;k<4;k++){ f4arr(*(const float4*)&sWq[(m+k)*68+d0], wq[k]); f4arr(*(const float4*)&sWk[(m+k)*68+d0], wk[k]); }
    float p[4];
    f4arr(pc0,p);
    #pragma unroll
    for (int k=0;k<4;k++)
      #pragma unroll
      for (int j=0;j<4;j++){ aq[0*4+j]+=p[k]*wq[k][j]; ak[0*4+j]+=p[k]*wk[k][j]; }
    f4arr(pc1,p);
    #pragma unroll
    for (int k=0;k<4;k++)
      #pragma unroll
      for (int j=0;j<4;j++){ aq[1*4+j]+=p[k]*wq[k][j]; ak[1*4+j]+=p[k]*wk[k][j]; }
    f4arr(pc2,p);
    #pragma unroll
    for (int k=0;k<4;k++)
      #pragma unroll
      for (int j=0;j<4;j++){ aq[2*4+j]+=p[k]*wq[k][j]; ak[2*4+j]+=p[k]*wk[k][j]; }
    f4arr(pc3,p);
    #pragma unroll
    for (int k=0;k<4;k++)
      #pragma unroll
      for (int j=0;j<4;j++){ aq[3*4+j]+=p[k]*wq[k][j]; ak[3*4+j]+=p[k]*wk[k][j]; }
    pc0=pn0; pc1=pn1; pc2=pn2; pc3=pn3;
  }
  float ssq=0.f, ssk=0.f;
  #pragma unroll
  for (int i=0;i<4;i++){
    int r=base+g+16*i;
    float4 Q=make_float4(aq[i*4+0],aq[i*4+1],aq[i*4+2],aq[i*4+3]);
    float4 K=make_float4(ak[i*4+0],ak[i*4+1],ak[i*4+2],ak[i*4+3]);
    ((float4*)(qout+(size_t)r*DD))[td]=Q;
    ((ushort4*)(qh+(size_t)r*DD))[td]=pk4(Q.x,Q.y,Q.z,Q.w);
    ((ushort4*)(kh+(size_t)r*DD))[td]=pk4(K.x,K.y,K.z,K.w);
    ssq += Q.x*Q.x+Q.y*Q.y+Q.z*Q.z+Q.w*Q.w;
    ssk += K.x*K.x+K.y*K.y+K.z*K.z+K.w*K.w;
  }
  #pragma unroll
  for (int j=0;j<4;j++){
    float cs = ak[0*4+j]+ak[1*4+j]+ak[2*4+j]+ak[3*4+j];
    atomicAdd(&sks[d0+j], cs);     // LDS atomic only
  }
  #pragma unroll
  for (int off=32;off;off>>=1){ ssq+=__shfl_down(ssq,off,64); ssk+=__shfl_down(ssk,off,64); }
  if ((t&63)==0){ sred[t>>6]=ssq; sred[4+(t>>6)]=ssk; }
  __syncthreads();
  float* my = slab + (size_t)blockIdx.x*66;
  if (t<64) my[t]=sks[t];
  if (t==0){ my[64]=sred[0]+sred[1]+sred[2]+sred[3]; my[65]=sred[4]+sred[5]+sred[6]+sred[7]; }
}

// wave-per-column fp32 psum — only for tiny n (qk: n=66)
__global__ __launch_bounds__(256) void k_psumW(const float* __restrict__ slab, int stride, int n, int P,
                                               float* __restrict__ out)
{
  int col=blockIdx.x*4+(threadIdx.x>>6);
  int lane=threadIdx.x&63;
  if (col>=n) return;
  float a0=0.f,a1=0.f;
  int p=lane;
  for (; p+64<P; p+=128){ a0+=slab[(size_t)p*stride+col]; a1+=slab[(size_t)(p+64)*stride+col]; }
  for (; p<P; p+=64) a0+=slab[(size_t)p*stride+col];
  float a=a0+a1;
  #pragma unroll
  for (int off=32;off;off>>=1) a+=__shfl_down(a,off,64);
  if (lane==0) out[col]=a;
}

// Coalesced two-level reductions (thread-per-column).
__global__ __launch_bounds__(256) void k_psumL1(const unsigned short* __restrict__ slab, int stride, int n, int P,
                                                float* __restrict__ part)
{
  int col=blockIdx.x*256+threadIdx.x;
  if (col>=n) return;
  int rc=blockIdx.y;
  int cp=P/NS;
  const unsigned short* p=slab+(size_t)(rc*cp)*stride+col;
  float a0=0,a1=0;
  int i=0;
  for (; i+2<=cp; i+=2){ a0+=bf2f(p[0]); a1+=bf2f(p[(size_t)stride]); p+=(size_t)2*stride; }
  for (; i<cp; i++){ a0+=bf2f(p[0]); p+=(size_t)stride; }
  part[(size_t)rc*n+col]=a0+a1;
}
__global__ __launch_bounds__(256) void k_psumL1f(const float* __restrict__ slab, int stride, int n, int P,
                                                 float* __restrict__ part)
{
  int col=blockIdx.x*256+threadIdx.x;
  if (col>=n) return;
  int rc=blockIdx.y;
  int cp=P/NS;
  const float* p=slab+(size_t)(rc*cp)*stride+col;
  float a0=0,a1=0;
  int i=0;
  for (; i+2<=cp; i+=2){ a0+=p[0]; a1+=p[(size_t)stride]; p+=(size_t)2*stride; }
  for (; i<cp; i++){ a0+=p[0]; p+=(size_t)stride; }
  part[(size_t)rc*n+col]=a0+a1;
}
__global__ __launch_bounds__(256) void k_psumL2(const float* __restrict__ part, int n, float* __restrict__ out)
{
  int col=blockIdx.x*256+threadIdx.x;
  if (col>=n) return;
  float a=0.f;
  #pragma unroll
  for (int rc=0;rc<NS;rc++) a += part[(size_t)rc*n+col];
  out[col]=a;
}

// compute normalization scalars; normalize ksum in place
__global__ void k_scalars(float* __restrict__ ksum, float* __restrict__ sc, const float* __restrict__ lin2){
  __shared__ float s_ki;
  int t=threadIdx.x;
  if (t==0){
    float fq=sqrtf(ksum[64]), fk=sqrtf(ksum[65]);
    float qi=1.f/fq, ki=1.f/fk;
    sc[0]=qi; sc[1]=ki; sc[2]=qi*ki; sc[3]=lin2[1]*qi; sc[4]=1.f;
    sc[5]=ki;    sc[6]=1.f; sc[7]=qi;   // TR_MAIN
    sc[8]=qi*ki; sc[9]=qi;  sc[10]=qi;  // TR_ZB2
    s_ki=ki;
  }
  __syncthreads();
  if (t<64) ksum[t]*=s_ki;
}

// gramc0 partials — bf16 q/k inputs, bf16 slab, GP=1008, register invn
__global__ __launch_bounds__(256) void k_gramc0p(const unsigned short* __restrict__ qh, const unsigned short* __restrict__ kh,
    const float* __restrict__ ksum, const float* __restrict__ sc,
    float* __restrict__ invn, unsigned short* __restrict__ slab)
{
  __shared__ float sk[16][64], sq[16][64], sw[16], sks[64];
  int t=threadIdx.x, tp=t&15, tm=t>>4;
  if (t<64) sks[t]=ksum[t];
  float qi_=sc[0];
  float akq[16], ag[16], ac0[16];
  #pragma unroll
  for (int i=0;i<16;i++){akq[i]=0.f;ag[i]=0.f;ac0[i]=0.f;}
  float rb[4]={0,0,0,0}, cb[4]={0,0,0,0}; float s22=0.f;
  int srow=t>>4, scol=(t&15)*4;
  for (int tile=blockIdx.x; tile<NN/16; tile+=gridDim.x){
    int base=tile*16;
    ((float4*)sk)[t]=up4(((const ushort4*)(kh+(size_t)base*DD))[t]);
    float4 qv=up4(((const ushort4*)(qh+(size_t)base*DD))[t]);
    ((float4*)sq)[t]=qv;
    {
      float p = qv.x*sks[scol] + qv.y*sks[scol+1] + qv.z*sks[scol+2] + qv.w*sks[scol+3];
      p += __shfl_xor(p,1,64); p += __shfl_xor(p,2,64);
      p += __shfl_xor(p,4,64); p += __shfl_xor(p,8,64);
      if ((t&15)==0){
        float w = 1.f/(p*qi_ + (float)NN);
        sw[srow]=w; invn[base+srow]=w;
      }
    }
    __syncthreads();
    #pragma unroll
    for (int r=0;r<16;r++){
      float w=sw[r];
      float km[4],qp[4],kp[4];
      f4arr(((const float4*)&sk[r][0])[tm], km);
      f4arr(((const float4*)&sq[r][0])[tp], qp);
      f4arr(((const float4*)&sk[r][0])[tp], kp);
      float wq[4]={w*qp[0],w*qp[1],w*qp[2],w*qp[3]};
      #pragma unroll
      for (int i=0;i<4;i++)
        #pragma unroll
        for (int j=0;j<4;j++){
          akq[i*4+j]+=km[i]*qp[j];
          ag [i*4+j]+=km[i]*kp[j];
          ac0[i*4+j]+=km[i]*wq[j];
        }
      if (tp==0){
        #pragma unroll
        for (int i=0;i<4;i++) rb[i]+=km[i]*w;
      }
      if (tm==0){
        #pragma unroll
        for (int j=0;j<4;j++) cb[j]+=wq[j];
      }
      if (t==0) s22+=w;
    }
    __syncthreads();
  }
  unsigned short* my = slab + (size_t)blockIdx.x*GSTRIDE;
  #pragma unroll
  for (int i=0;i<4;i++){
    int a=tm*4+i;
    *(ushort4*)(my +        a*DD + tp*4) = pk4(akq[i*4+0],akq[i*4+1],akq[i*4+2],akq[i*4+3]);
    *(ushort4*)(my + 4096 + a*DD + tp*4) = pk4(ag [i*4+0],ag [i*4+1],ag [i*4+2],ag [i*4+3]);
    *(ushort4*)(my + 8192 + a*68 + tp*4) = pk4(ac0[i*4+0],ac0[i*4+1],ac0[i*4+2],ac0[i*4+3]);
  }
  if (tp==0){
    #pragma unroll
    for (int i=0;i<4;i++) my[8192 + (tm*4+i)*68 + 64] = f2bf(rb[i]);
  }
  if (tm==0){
    *(ushort4*)(my + 8192 + 64*68 + tp*4) = pk4(cb[0],cb[1],cb[2],cb[3]);
  }
  if (t==0) my[8192 + 64*68 + 64] = f2bf(s22);
}

// normalize KQ, G, C0(stride-68)
__global__ void k_applyscale(float* __restrict__ KQ, float* __restrict__ G, float* __restrict__ C0,
                             const float* __restrict__ sc){
  int i=blockIdx.x*256+threadIdx.x;
  float qi=sc[0], ki=sc[1], qk=sc[2];
  if (i<4096){ KQ[i]*=qk; G[i]*=ki*ki; }
  if (i<4420){
    int a=i/68, b=i-68*a;
    float s = (a<64)? (b<64? qk : ki) : (b<64? qi : 1.f);
    C0[i]*=s;
  }
}

// H partials — fp32 slab, RP=512 (q2=tmpM fp32)
__global__ __launch_bounds__(256) void k_Hp(const float* __restrict__ q2, const float* __restrict__ wv,
                                            float* __restrict__ slab)
{
  __shared__ float sq[16][64], sw[16];
  int t=threadIdx.x, tp=t&15, tm=t>>4;
  float acc[16];
  #pragma unroll
  for (int i=0;i<16;i++) acc[i]=0.f;
  for (int tile=blockIdx.x; tile<NN/16; tile+=gridDim.x){
    int base=tile*16;
    ((float4*)sq)[t]=((const float4*)(q2+(size_t)base*DD))[t];
    if (t<16) sw[t]=wv[base+t];
    __syncthreads();
    #pragma unroll
    for (int r=0;r<16;r++){
      float w=sw[r]; w=w*w;
      float qm[4],qp[4];
      f4arr(((const float4*)&sq[r][0])[tm], qm);
      f4arr(((const float4*)&sq[r][0])[tp], qp);
      float wq[4]={w*qp[0],w*qp[1],w*qp[2],w*qp[3]};
      #pragma unroll
      for (int i=0;i<4;i++)
        #pragma unroll
        for (int j=0;j<4;j++) acc[i*4+j]+=qm[i]*wq[j];
    }
    __syncthreads();
  }
  float* my = slab + (size_t)blockIdx.x*4096;
  #pragma unroll
  for (int i=0;i<4;i++)
    #pragma unroll
    for (int j=0;j<4;j++) my[(tm*4+i)*DD+tp*4+j] = acc[i*4+j];
}

// z partials — bf16 k input, fp32 v, fp32 slab, RP=512
__global__ __launch_bounds__(256) void k_redp(const unsigned short* __restrict__ kh, const float* __restrict__ v,
                                              float* __restrict__ slab)
{
  __shared__ float sk[16][64], sv[16][64];
  int t=threadIdx.x, tp=t&15, tm=t>>4;
  float acc[16];
  #pragma unroll
  for (int i=0;i<16;i++) acc[i]=0.f;
  float cs[4]={0,0,0,0};
  for (int tile=blockIdx.x; tile<NN/16; tile+=gridDim.x){
    int base=tile*16;
    ((float4*)sk)[t]=up4(((const ushort4*)(kh+(size_t)base*DD))[t]);
    ((float4*)sv)[t]=((const float4*)(v+(size_t)base*DD))[t];
    __syncthreads();
    #pragma unroll
    for (int r=0;r<16;r++){
      float km[4],vd[4];
      f4arr(((const float4*)&sk[r][0])[tm], km);
      f4arr(((const float4*)&sv[r][0])[tp], vd);
      #pragma unroll
      for (int i=0;i<4;i++)
        #pragma unroll
        for (int j=0;j<4;j++) acc[i*4+j]+=km[i]*vd[j];
      if (tm==0){
        #pragma unroll
        for (int j=0;j<4;j++) cs[j]+=vd[j];
      }
    }
    __syncthreads();
  }
  float* my = slab + (size_t)blockIdx.x*4160;
  #pragma unroll
  for (int i=0;i<4;i++)
    #pragma unroll
    for (int j=0;j<4;j++) my[(tm*4+i)*DD+tp*4+j] = acc[i*4+j];
  if (tm==0){
    #pragma unroll
    for (int j=0;j<4;j++) my[64*DD+tp*4+j] = cs[j];
  }
}

// zf = Cfin * z_scaled with scalar folding
__global__ void k_zfin(const float* __restrict__ Cfin, const float* __restrict__ z, float* __restrict__ zf,
                       const float* __restrict__ sc3){
  int a=blockIdx.x, d=threadIdx.x;
  float it=sc3[0], ib=sc3[1], ot=sc3[2];
  float acc=0.f;
  for (int b=0;b<64;b++) acc += Cfin[a*65+b]*z[b*DD+d];
  acc = acc*it + Cfin[a*65+64]*ib*z[64*DD+d];
  zf[a*DD+d] = (a<64? ot:1.f)*acc;
}
__global__ void k_zB(const float* __restrict__ KQ, const float* __restrict__ z, float* __restrict__ zf,
                     const float* __restrict__ sc3){
  int a=blockIdx.x, d=threadIdx.x;
  float it=sc3[0], ib=sc3[1], ot=sc3[2];
  float acc;
  if (a<64){ acc=0.f; for (int m=0;m<64;m++) acc += KQ[a*DD+m]*z[m*DD+d]; acc*=it*ot; }
  else acc = ib*z[64*DD+d];
  zf[a*DD+d]=acc;
}

// expand — bf16 q input, staged sQ/sZ, bounded unroll
__global__ __launch_bounds__(256) void k_expand(const unsigned short* __restrict__ qh,
    const float* __restrict__ Zf, const float* __restrict__ invn, const float* __restrict__ sdeg,
    const float* __restrict__ self, const float* __restrict__ coefp, int cidx,
    unsigned short* __restrict__ outv)
{
  __shared__ float sQ[64*68];
  __shared__ float sZ[65*64];
  int t=threadIdx.x;
  int base=blockIdx.x*64;
  for (int i=t;i<1040;i+=256) ((float4*)sZ)[i]=((const float4*)Zf)[i];
  for (int i=t;i<1024;i+=256){
    int r=i>>4, c4=i&15;
    float4 v=up4(((const ushort4*)(qh+(size_t)(base+r)*DD))[c4]);
    float* dst=&sQ[r*68+c4*4]; dst[0]=v.x;dst[1]=v.y;dst[2]=v.z;dst[3]=v.w;
  }
  __syncthreads();
  int td=t&15, g=t>>4, d0=td*4;
  float acc[16];
  {
    float ones[4]; f4arr(*(const float4*)&sZ[64*DD+d0], ones);
    #pragma unroll
    for (int i=0;i<4;i++)
      #pragma unroll
      for (int j=0;j<4;j++) acc[i*4+j]=ones[j];
  }
  #pragma unroll 2
  for (int m=0;m<64;m+=4){
    float zr[4][4];
    #pragma unroll
    for (int k=0;k<4;k++) f4arr(*(const float4*)&sZ[(m+k)*DD+d0], zr[k]);
    #pragma unroll
    for (int i=0;i<4;i++){
      float p[4]; f4arr(*(const float4*)&sQ[(g+16*i)*68+m], p);
      #pragma unroll
      for (int k=0;k<4;k++)
        #pragma unroll
        for (int j=0;j<4;j++) acc[i*4+j]+=p[k]*zr[k][j];
    }
  }
  bool hasself=(cidx>=0);
  float cc = hasself ? coefp[cidx] : 0.f;
  #pragma unroll
  for (int i=0;i<4;i++){
    int r=base+g+16*i;
    float w=invn[r];
    float sd=sdeg[r];
    float4 o=make_float4(acc[i*4+0]*w,acc[i*4+1]*w,acc[i*4+2]*w,acc[i*4+3]*w);
    if (hasself){
      float4 s4=((const float4*)(self+(size_t)r*DD))[td];
      o.x+=cc*s4.x; o.y+=cc*s4.y; o.z+=cc*s4.z; o.w+=cc*s4.w;
    }
    o.x*=sd; o.y*=sd; o.z*=sd; o.w*=sd;
    ushort4 o4; o4.x=f2bf(o.x); o4.y=f2bf(o.y); o4.z=f2bf(o.z); o4.w=f2bf(o.w);
    ((ushort4*)(outv+(size_t)r*DD))[td]=o4;
  }
}

// ---- tiny 65-dim matrix kernels (C0 stride-68) ----
__global__ void k_makeC(const float* __restrict__ C0, const float* __restrict__ KQ, float* __restrict__ C){
  int a=blockIdx.x, d=threadIdx.x;
  float acc=0.f;
  for (int m=0;m<64;m++) acc += C0[a*68+m]*KQ[m*DD+d];
  C[a*65+d]=acc;
  if (d==0) C[a*65+64]=C0[a*68+64];
}
__global__ void k_makeCmix(const float* __restrict__ C, const float* __restrict__ lin2, float* __restrict__ Cmix){
  int a=blockIdx.x, c=threadIdx.x;
  if (c>=65) return;
  float b1=lin2[1], b2=lin2[2], b3=lin2[3];
  float acc=0.f;
  for (int b=0;b<65;b++) acc += C[a*65+b]*C[b*65+c];
  float r = b2*C[a*65+c] + b3*acc;
  if (a==c) r += b1;
  Cmix[a*65+c]=r;
}
__global__ void k_makeCfin(const float* __restrict__ KQ, const float* __restrict__ Cmix, float* __restrict__ Cfin){
  int a=blockIdx.x, c=threadIdx.x;
  if (c>=65) return;
  float acc;
  if (a<64){ acc=0.f; for (int m=0;m<64;m++) acc += KQ[a*DD+m]*Cmix[m*65+c]; }
  else acc = Cmix[64*65+c];
  Cfin[a*65+c]=acc;
}

// ---- CSR build of transpose adjacency, zero global atomics ----
__global__ __launch_bounds__(256) void k_hist2(const int* __restrict__ acols, unsigned int* __restrict__ slab){
  __shared__ unsigned int lc[16384];
  int t=threadIdx.x;
  for (int i=t;i<16384;i+=256) lc[i]=0u;
  __syncthreads();
  int e0=blockIdx.x*EPB;
  for (int i=t;i<EPB;i+=256){
    int c=acols[e0+i];
    atomicAdd(&lc[c>>2], 1u<<((c&3)*8));
  }
  __syncthreads();
  unsigned int* my=slab+(size_t)blockIdx.x*16384;
  for (int i=t;i<16384;i+=256) my[i]=lc[i];
}

__global__ __launch_bounds__(256) void k_pscan(unsigned int* __restrict__ slab, int* __restrict__ cnt,
                                               float* __restrict__ sdeg, float* __restrict__ accs){
  int w=blockIdx.x*256+threadIdx.x;
  unsigned int r0=0,r1=0,r2=0,r3=0;
  for (int b=0;b<B1;b++){
    unsigned int v=slab[(size_t)b*16384+w];
    slab[(size_t)b*16384+w] = r0|(r1<<8)|(r2<<16)|(r3<<24);
    r0+=v&255u; r1+=(v>>8)&255u; r2+=(v>>16)&255u; r3+=(v>>24)&255u;
  }
  ((int4*)cnt)[w]=make_int4((int)r0,(int)r1,(int)r2,(int)r3);
  float d0=(float)r0+9.f, d1=(float)r1+9.f, d2=(float)r2+9.f, d3=(float)r3+9.f;
  float s0=1.f/sqrtf(d0), s1=1.f/sqrtf(d1), s2=1.f/sqrtf(d2), s3=1.f/sqrtf(d3);
  ((float4*)sdeg)[w]=make_float4(s0,s1,s2,s3);
  float t3 = 1.f/(d0*d0)+1.f/(d1*d1)+1.f/(d2*d2)+1.f/(d3*d3);
  #pragma unroll
  for (int off=32;off;off>>=1) t3+=__shfl_down(t3,off,64);
  if ((threadIdx.x&63)==0) atomicAdd(&accs[1], t3);
}

__global__ __launch_bounds__(1024) void k_scan(const int* __restrict__ cnt, int* __restrict__ row_start){
  __shared__ int wtot[16];
  int t=threadIdx.x, lane=t&63, wid=t>>6;
  int base=t*64;
  int s=0;
  for (int i=0;i<64;i++) s+=cnt[base+i];
  int tot=s;
  for (int off=1;off<64;off<<=1){ int v=__shfl_up(s,off,64); if(lane>=off) s+=v; }
  if (lane==63) wtot[wid]=s;
  __syncthreads();
  if (t<16){
    int v=wtot[t];
    for (int off=1;off<16;off<<=1){ int u=__shfl_up(v,off,64); if(t>=off) v+=u; }
    wtot[t]=v;
  }
  __syncthreads();
  int excl = s - tot + (wid? wtot[wid-1]:0);
  int run=excl;
  for (int i=0;i<64;i++){ row_start[base+i]=run; run+=cnt[base+i]; }
  if (t==1023) row_start[NN]=run;
}

__global__ __launch_bounds__(256) void k_scatter2(const int* __restrict__ acols,
    const unsigned int* __restrict__ slab, const int* __restrict__ row_start,
    const float* __restrict__ sdeg, unsigned short* __restrict__ ccols16, float* __restrict__ accs){
  __shared__ unsigned int lc[16384];
  int t=threadIdx.x;
  for (int i=t;i<16384;i+=256) lc[i]=0u;
  __syncthreads();
  int e0=blockIdx.x*EPB;
  const unsigned int* my=slab+(size_t)blockIdx.x*16384;
  float t3=0.f;
  for (int i=t;i<EPB;i+=256){
    int e=e0+i;
    int c=acols[e];
    unsigned int sh=(unsigned int)(c&3)*8u;
    unsigned int old=atomicAdd(&lc[c>>2], 1u<<sh);
    unsigned int lp=(old>>sh)&255u;
    unsigned int pref=(my[c>>2]>>sh)&255u;
    int slot=row_start[c]+(int)pref+(int)lp;
    ccols16[slot]=(unsigned short)(e>>3);
    float sp=sdeg[e>>3]*sdeg[c];
    t3 += 2.f*sp*sp;
  }
  #pragma unroll
  for (int off=32;off;off>>=1) t3+=__shfl_down(t3,off,64);
  __shared__ float sred[4];
  if ((t&63)==0) sred[t>>6]=t3;
  __syncthreads();
  if (t==0) atomicAdd(&accs[1], sred[0]+sred[1]+sred[2]+sred[3]);
}

// Structural SpMM over bf16 xs
__global__ __launch_bounds__(256) void k_spmm2(const int* __restrict__ row_start,
    const unsigned short* __restrict__ ccols16, const int* __restrict__ acols,
    const float* __restrict__ sdeg,
    const unsigned short* __restrict__ xs, float* __restrict__ outv, int wout,
    float* __restrict__ accbuf, const float* __restrict__ coefp, int cidx,
    const float* __restrict__ initsrc, int initc, const float* __restrict__ iscale)
{
  int lane=threadIdx.x&63;
  int row=blockIdx.x*4+(threadIdx.x>>6);
  int s=row_start[row], e=row_start[row+1];
  int din=e-s;
  int dc=din>56?56:din;
  int L=8+dc;
  int myc=0;
  if (lane<8) myc=acols[row*8+lane];
  else if (lane<L) myc=(int)ccols16[s+lane-8];
  float a0=0,a1=0,a2=0,a3=0,a4=0,a5=0,a6=0,a7=0;
  int i=0;
  for (; i+8<=L; i+=8){
    int c0=__shfl(myc,i  ,64), c1=__shfl(myc,i+1,64), c2=__shfl(myc,i+2,64), c3=__shfl(myc,i+3,64);
    int c4=__shfl(myc,i+4,64), c5=__shfl(myc,i+5,64), c6=__shfl(myc,i+6,64), c7=__shfl(myc,i+7,64);
    float v0=bf2f(xs[(size_t)c0*DD+lane]), v1=bf2f(xs[(size_t)c1*DD+lane]);
    float v2=bf2f(xs[(size_t)c2*DD+lane]), v3=bf2f(xs[(size_t)c3*DD+lane]);
    float v4=bf2f(xs[(size_t)c4*DD+lane]), v5=bf2f(xs[(size_t)c5*DD+lane]);
    float v6=bf2f(xs[(size_t)c6*DD+lane]), v7=bf2f(xs[(size_t)c7*DD+lane]);
    a0+=v0; a1+=v1; a2+=v2; a3+=v3; a4+=v4; a5+=v5; a6+=v6; a7+=v7;
  }
  for (; i+4<=L; i+=4){
    int c0=__shfl(myc,i,64), c1=__shfl(myc,i+1,64), c2=__shfl(myc,i+2,64), c3=__shfl(myc,i+3,64);
    a0+=bf2f(xs[(size_t)c0*DD+lane]); a1+=bf2f(xs[(size_t)c1*DD+lane]);
    a2+=bf2f(xs[(size_t)c2*DD+lane]); a3+=bf2f(xs[(size_t)c3*DD+lane]);
  }
  for (; i<L; ++i){
    int c=__shfl(myc,i,64);
    a0 += bf2f(xs[(size_t)c*DD+lane]);
  }
  for (int j=56;j<din;j++){ int c=(int)ccols16[s+j]; a0+=bf2f(xs[(size_t)c*DD+lane]); }
  float acc=((a0+a1)+(a2+a3))+((a4+a5)+(a6+a7));
  acc += bf2f(xs[(size_t)row*DD+lane]);
  acc *= sdeg[row];
  size_t off=(size_t)row*DD+lane;
  if (wout) outv[off]=acc;
  if (cidx>=0){
    float cc=coefp[cidx];
    float base;
    if (initc>=0){
      float isc = iscale ? *iscale : coefp[initc];
      base = isc*initsrc[off];
    } else base = accbuf[off];
    accbuf[off]=base+cc*acc;
  }
}

// kns(bf16)[n][d] = sdeg[n]*k_bf16[n][d]*(1/fk)
__global__ __launch_bounds__(256) void k_scalerows(const unsigned short* __restrict__ kh, const float* __restrict__ sdeg,
                                                   const float* __restrict__ sc, unsigned short* __restrict__ kns){
  float ki=sc[1];
  int i=blockIdx.x*256+threadIdx.x;
  int stride=gridDim.x*256;
  for (; i<ND/4; i+=stride){
    float sd=sdeg[i>>4]*ki;
    float4 v=up4(((const ushort4*)kh)[i]);
    ((ushort4*)kns)[i]=pk4(sd*v.x,sd*v.y,sd*v.z,sd*v.w);
  }
}

// t2 partials — bf16 gathers, no global atomics
__global__ __launch_bounds__(256) void k_t2v(const int* __restrict__ row_start,
    const unsigned short* __restrict__ ccols16, const int* __restrict__ acols,
    const float* __restrict__ sdeg, const unsigned short* __restrict__ kns,
    const float* __restrict__ q2, const float* __restrict__ w, float* __restrict__ t2out)
{
  int lane=threadIdx.x&63;
  int wid=blockIdx.x*4+(threadIdx.x>>6);
  int nw=gridDim.x*4;
  float t=0.f;
  for (int row=wid; row<NN; row+=nw){
    int s=row_start[row], e=row_start[row+1];
    int din=e-s;
    int dc=din>56?56:din;
    int L=8+dc;
    int myc=0;
    if (lane<8) myc=acols[row*8+lane];
    else if (lane<L) myc=(int)ccols16[s+lane-8];
    float a0=0,a1=0,a2=0,a3=0,a4=0,a5=0,a6=0,a7=0;
    int i=0;
    for (; i+8<=L; i+=8){
      int c0=__shfl(myc,i  ,64), c1=__shfl(myc,i+1,64), c2=__shfl(myc,i+2,64), c3=__shfl(myc,i+3,64);
      int c4=__shfl(myc,i+4,64), c5=__shfl(myc,i+5,64), c6=__shfl(myc,i+6,64), c7=__shfl(myc,i+7,64);
      a0+=bf2f(kns[(size_t)c0*DD+lane]); a1+=bf2f(kns[(size_t)c1*DD+lane]);
      a2+=bf2f(kns[(size_t)c2*DD+lane]); a3+=bf2f(kns[(size_t)c3*DD+lane]);
      a4+=bf2f(kns[(size_t)c4*DD+lane]); a5+=bf2f(kns[(size_t)c5*DD+lane]);
      a6+=bf2f(kns[(size_t)c6*DD+lane]); a7+=bf2f(kns[(size_t)c7*DD+lane]);
    }
    for (; i+4<=L; i+=4){
      int c0=__shfl(myc,i,64), c1=__shfl(myc,i+1,64), c2=__shfl(myc,i+2,64), c3=__shfl(myc,i+3,64);
      a0+=bf2f(kns[(size_t)c0*DD+lane]); a1+=bf2f(kns[(size_t)c1*DD+lane]);
      a2+=bf2f(kns[(size_t)c2*DD+lane]); a3+=bf2f(kns[(size_t)c3*DD+lane]);
    }
    for (; i<L; ++i){
      int c=__shfl(myc,i,64);
      a0 += bf2f(kns[(size_t)c*DD+lane]);
    }
    for (int j=56;j<din;j++){ int c=(int)ccols16[s+j]; a0+=bf2f(kns[(size_t)c*DD+lane]); }
    float acc=((a0+a1)+(a2+a3))+((a4+a5)+(a6+a7));
    acc += bf2f(kns[(size_t)row*DD+lane]);
    t += w[row]*q2[(size_t)row*DD+lane]*sdeg[row]*acc;
  }
  #pragma unroll
  for (int off=32;off;off>>=1) t+=__shfl_down(t,off,64);
  __shared__ float sred[4];
  if ((threadIdx.x&63)==0) sred[threadIdx.x>>6]=t;
  __syncthreads();
  if (threadIdx.x==0) t2out[blockIdx.x]=sred[0]+sred[1]+sred[2]+sred[3];
}

// per-chunk inverse frobenius of gq
__global__ __launch_bounds__(256) void k_chunk(const float* __restrict__ gq, float* __restrict__ chunk_inv){
  int c=blockIdx.x;
  const float4* p=(const float4*)(gq + (size_t)c*65536);
  float ss=0.f;
  for (int i=threadIdx.x;i<16384;i+=256){ float4 v=p[i]; ss += v.x*v.x+v.y*v.y+v.z*v.z+v.w*v.w; }
  __shared__ float red[4];
  #pragma unroll
  for (int off=32;off;off>>=1) ss+=__shfl_down(ss,off,64);
  if ((threadIdx.x&63)==0) red[threadIdx.x>>6]=ss;
  __syncthreads();
  if (threadIdx.x==0){ float s=red[0]+red[1]+red[2]+red[3]; chunk_inv[c]=1.f/sqrtf(s); }
}

// gq *= chunk_inv; nrm2inv
__global__ __launch_bounds__(256) void k_nrm2(float* __restrict__ gq, const float* __restrict__ chunk_inv,
                                              const float* __restrict__ ks, float* __restrict__ nrm2inv){
  __shared__ float sks[64];
  if (threadIdx.x<64) sks[threadIdx.x]=ks[threadIdx.x];
  __syncthreads();
  int lane=threadIdx.x&63;
  int wid=blockIdx.x*4+(threadIdx.x>>6);
  int nw=gridDim.x*4;
  for (int row=wid;row<NN;row+=nw){
    float q=gq[(size_t)row*DD+lane]*chunk_inv[row>>10];
    gq[(size_t)row*DD+lane]=q;
    float p=q*sks[lane];
    #pragma unroll
    for (int off=32;off;off>>=1) p+=__shfl_down(p,off,64);
    if (lane==0) nrm2inv[row]=1.f/(p+1024.f);
  }
}

__global__ void k_final(const float* __restrict__ G, const float* __restrict__ H,
                        const float* __restrict__ t2s, const float* __restrict__ accs,
                        const float* __restrict__ lin2, float* __restrict__ outv){
  __shared__ float red[256];
  __shared__ float gh;
  int t=threadIdx.x;
  float s=0.f;
  for (int i=t;i<4096;i+=256) s+=G[i]*H[i];
  red[t]=s;
  __syncthreads();
  for (int k=128;k;k>>=1){ if (t<k) red[t]+=red[t+k]; __syncthreads(); }
  if (t==0) gh=red[0];
  __syncthreads();
  float s2=0.f;
  for (int i=t;i<2048;i+=256) s2+=t2s[i];
  red[t]=s2;
  __syncthreads();
  for (int k=128;k;k>>=1){ if (t<k) red[t]+=red[t+k]; __syncthreads(); }
  if (t==0){
    float c0=lin2[0]-1.f;
    outv[0]=sqrtf(gh + 2.f*c0*red[0] + c0*c0*accs[1]);
  }
}

extern "C" void kernel_launch(void* const* d_in, const int* in_sizes, int n_in,
                              void* d_out, int out_size, void* d_ws, size_t ws_size,
                              hipStream_t stream)
{
  (void)n_in; (void)out_size; (void)ws_size; (void)in_sizes;
  const float* preds = (const float*)d_in[0];
  const int*   acols = (const int*)d_in[3];
  const float* Wq    = (const float*)d_in[5];
  const float* bq    = (const float*)d_in[6];
  const float* Wk    = (const float*)d_in[7];
  const float* bk    = (const float*)d_in[8];
  const float* lin1  = (const float*)d_in[9];
  const float* lin2  = (const float*)d_in[10];
  float* outp = (float*)d_out;

  float* W    = (float*)d_ws;
  float* q    = W;                                    // fp32 q (loss seed only)
  unsigned short* qh = (unsigned short*)(W + ND);     // bf16 q (ND ushorts)
  unsigned short* kh = qh + (size_t)ND;               // bf16 k (ND ushorts) — together = old k slot
  float* tmpM = W + 2*(size_t)ND;
  unsigned short* mixh = (unsigned short*)(W + 3*(size_t)ND);
  float* bufv = W + 3*(size_t)ND + ND/2;
  float* invn = bufv + (size_t)ND;
  float* sdeg = invn + NN;
  float* sm   = sdeg + NN;
  int* cnt       = (int*)(sm + SM_END);
  int* row_start = cnt + NN;
  unsigned short* ccols16 = (unsigned short*)(row_start + NN + 1);
  float* slab = (float*)(ccols16 + E0);             // ~26MB region: fp32 view (qk, redp, Hp)
  unsigned short* slab16 = (unsigned short*)slab;   // bf16 view (gramc0p)
  float* part = slab + (size_t)GP*GSTRIDE/2 + 64;   // NS x 12612 fp32 L1 partials

  unsigned int* hist_slab = (unsigned int*)tmpM;
  unsigned short* knsh = mixh;

  float* sc=sm+SM_SCAL;
  float* KQ=sm+SM_KQ; float* G=sm+SM_G; float* H=sm+SM_H;
  float* z=sm+SM_Z; float* zf=sm+SM_ZF;
  float* C0=sm+SM_C0; float* C=sm+SM_C; float* Cmix=sm+SM_CMIX; float* Cfin=sm+SM_CFIN;

  hipMemsetAsync(sm, 0, 24*sizeof(float), stream);

  k_qk<<<QKP,256,0,stream>>>(preds,Wq,bq,Wk,bk,q,qh,kh,slab);
  k_psumW<<<(66+3)/4,256,0,stream>>>(slab, 66, 66, QKP, sm+SM_KSUM);
  k_scalars<<<1,64,0,stream>>>(sm+SM_KSUM, sc, lin2);
  k_gramc0p<<<GP,256,0,stream>>>(qh,kh,sm+SM_KSUM,sc,invn,slab16);
  k_psumL1<<<dim3(50,NS),256,0,stream>>>(slab16, GSTRIDE, 12612, GP, part);
  k_psumL2<<<50,256,0,stream>>>(part, 12612, KQ);   // fills KQ,G,C0(68) raw
  k_applyscale<<<18,256,0,stream>>>(KQ,G,C0,sc);
  k_makeC<<<65,64,0,stream>>>(C0,KQ,C);
  k_makeCmix<<<65,128,0,stream>>>(C,lin2,Cmix);
  k_makeCfin<<<65,128,0,stream>>>(KQ,Cmix,Cfin);

  // CSR build of transpose adjacency (zero global atomics)
  k_hist2<<<B1,256,0,stream>>>(acols, hist_slab);
  k_pscan<<<64,256,0,stream>>>(hist_slab, cnt, sdeg, sm+SM_ACC);
  k_scan<<<1,1024,0,stream>>>(cnt, row_start);
  k_scatter2<<<B1,256,0,stream>>>(acols, hist_slab, row_start, sdeg, ccols16, sm+SM_ACC);

  // ----- main Hop-Stack loop -----
  for (int i=1;i<4;i++){
    const float* v = (i==1) ? preds : tmpM;
    k_redp<<<RP,256,0,stream>>>(kh,v,slab);
    k_psumL1f<<<dim3(17,NS),256,0,stream>>>(slab, 4160, 4160, RP, part);
    k_psumL2<<<17,256,0,stream>>>(part, 4160, z);
    k_zfin<<<65,64,0,stream>>>(Cfin,z,zf, sc+5);
    k_expand<<<1024,256,0,stream>>>(qh,zf,invn,sdeg,v,lin2,0,mixh);
    if (i==1)
      k_spmm2<<<16384,256,0,stream>>>(row_start,ccols16,acols,sdeg,mixh,tmpM,1,outp,lin1,1,preds,0,nullptr);
    else
      k_spmm2<<<16384,256,0,stream>>>(row_start,ccols16,acols,sdeg,mixh,tmpM,1,outp,lin1,i,nullptr,-1,nullptr);
  }

  // ----- residual loss branch -----
  k_redp<<<RP,256,0,stream>>>(kh,q,slab);
  k_psumL1f<<<dim3(17,NS),256,0,stream>>>(slab, 4160, 4160, RP, part);
  k_psumL2<<<17,256,0,stream>>>(part, 4160, z);
  k_zB<<<65,64,0,stream>>>(KQ,z,zf, sc+8);
  k_expand<<<1024,256,0,stream>>>(qh,zf,invn,sdeg,nullptr,nullptr,-1,mixh);
  k_spmm2<<<16384,256,0,stream>>>(row_start,ccols16,acols,sdeg,mixh,bufv,1,tmpM,lin2,2,q,1,sc+3);
  k_redp<<<RP,256,0,stream>>>(kh,bufv,slab);
  k_psumL1f<<<dim3(17,NS),256,0,stream>>>(slab, 4160, 4160, RP, part);
  k_psumL2<<<17,256,0,stream>>>(part, 4160, z);
  k_zB<<<65,64,0,stream>>>(KQ,z,zf, sc+5);
  k_expand<<<1024,256,0,stream>>>(qh,zf,invn,sdeg,nullptr,nullptr,-1,mixh);
  k_spmm2<<<16384,256,0,stream>>>(row_start,ccols16,acols,sdeg,mixh,nullptr,0,tmpM,lin2,3,nullptr,-1,nullptr);

  k_chunk<<<64,256,0,stream>>>(tmpM, sm+SM_CHUNK);
  k_nrm2<<<2048,256,0,stream>>>(tmpM, sm+SM_CHUNK, sm+SM_KSUM, invn);
  k_scalerows<<<1024,256,0,stream>>>(kh, sdeg, sc, knsh);
  k_Hp<<<RP,256,0,stream>>>(tmpM, invn, slab);
  k_psumL1f<<<dim3(16,NS),256,0,stream>>>(slab, 4096, 4096, RP, part);
  k_psumL2<<<16,256,0,stream>>>(part, 4096, H);
  k_t2v<<<2048,256,0,stream>>>(row_start,ccols16,acols,sdeg,knsh,tmpM,invn,sm+SM_T2);
  k_final<<<1,256,0,stream>>>(G,H,sm+SM_T2,sm+SM_ACC,lin2,outp+ND);
}